// Round 2
// baseline (699.173 us; speedup 1.0000x reference)
//
#include <hip/hip_runtime.h>
#include <type_traits>

typedef __attribute__((ext_vector_type(8))) short short8;
typedef __attribute__((ext_vector_type(4))) float f32x4;
typedef unsigned short u16;

__device__ __forceinline__ float bf2f(u16 u) {
    union { unsigned int i; float f; } x; x.i = ((unsigned int)u) << 16; return x.f;
}
__device__ __forceinline__ u16 f2bf(float f) {
    union { float f; unsigned int i; } x; x.f = f;
    unsigned int r = x.i + 0x7FFFu + ((x.i >> 16) & 1u);
    return (u16)(r >> 16);
}
__device__ __forceinline__ short8 cvt8(float4 v0, float4 v1) {
    union { u16 u[8]; short8 s; } p;
    p.u[0] = f2bf(v0.x); p.u[1] = f2bf(v0.y); p.u[2] = f2bf(v0.z); p.u[3] = f2bf(v0.w);
    p.u[4] = f2bf(v1.x); p.u[5] = f2bf(v1.y); p.u[6] = f2bf(v1.z); p.u[7] = f2bf(v1.w);
    return p.s;
}

// ---------------------------------------------------------------------------
// Fused weight transpose+concat+bf16: 6 jobs in one launch.
// out[n*512+k] = (k<Ka ? A[k][n] : B[k-Ka][n]); out is [N,512] bf16 W^T.
// ---------------------------------------------------------------------------
struct TCJobs {
    const float* A[6];
    const float* Bm[6];
    u16* out[6];
    int N[6];
    int Ka[6];
};

__global__ void transcat6_k(TCJobs j) {
    int jid = blockIdx.y;
    int i = blockIdx.x * 256 + threadIdx.x;
    int N = j.N[jid];
    if (i >= N * 512) return;
    int n = i >> 9, k = i & 511, Ka = j.Ka[jid];
    float v = (k < Ka) ? j.A[jid][k * N + n] : j.Bm[jid][(k - Ka) * N + n];
    j.out[jid][i] = f2bf(v);
}

// ---------------------------------------------------------------------------
// LDS-free MFMA GEMM: C[M,N] = act(A[M,512] @ WT[N,512]^T + bias)
// One wave per 64x64 output tile; A/B fragments loaded straight from global
// (B is L2-resident; A re-reads across the 4 N-tiles are absorbed by L3 since
// grid.x = N-tiles dispatches them back-to-back). No LDS, no barriers -> the
// compiler software-pipelines the K loop; occupancy is VGPR-limited only.
// AT = float (RNE-convert to bf16 in-reg) or u16 (bf16 raw).
// ACT: 0 none, 1 relu, 2 sigmoid. OT = u16 (bf16) or float.
// ---------------------------------------------------------------------------
template <typename AT, int ACT, typename OT>
__global__ __launch_bounds__(256) void gemm_nl_k(const AT* __restrict__ A,
                                                 const u16* __restrict__ WT,
                                                 const float* __restrict__ bias,
                                                 OT* __restrict__ C, int M, int N) {
    const int K = 512;
    const int lane = threadIdx.x & 63;
    const int w = threadIdx.x >> 6;
    const int m_base = blockIdx.y * 256 + w * 64;
    const int n_base = blockIdx.x * 64;
    const int lr = lane & 15;        // row within 16
    const int kq = (lane >> 4) * 8;  // per-lane-group k offset

    int arow[4];
    #pragma unroll
    for (int mi = 0; mi < 4; ++mi) {
        int r = m_base + mi * 16 + lr;
        arow[mi] = r < M ? r : M - 1;
    }
    const u16* wbase = WT + (size_t)n_base * K;

    f32x4 acc[4][4] = {};

    #pragma unroll 4
    for (int kt = 0; kt < K; kt += 32) {
        int kk = kt + kq;
        short8 a[4], b[4];
        #pragma unroll
        for (int ni = 0; ni < 4; ++ni)
            b[ni] = *(const short8*)&wbase[(size_t)(ni * 16 + lr) * K + kk];
        #pragma unroll
        for (int mi = 0; mi < 4; ++mi) {
            if constexpr (std::is_same<AT, float>::value) {
                float4 v0 = *(const float4*)&A[(size_t)arow[mi] * K + kk];
                float4 v1 = *(const float4*)&A[(size_t)arow[mi] * K + kk + 4];
                a[mi] = cvt8(v0, v1);
            } else {
                a[mi] = *(const short8*)&A[(size_t)arow[mi] * K + kk];
            }
        }
        #pragma unroll
        for (int mi = 0; mi < 4; ++mi)
            #pragma unroll
            for (int ni = 0; ni < 4; ++ni)
                acc[mi][ni] = __builtin_amdgcn_mfma_f32_16x16x32_bf16(
                    a[mi], b[ni], acc[mi][ni], 0, 0, 0);
    }

    // epilogue: C/D layout col=lane&15, row=(lane>>4)*4+reg  [m89 verified]
    #pragma unroll
    for (int mi = 0; mi < 4; ++mi) {
        int row0 = m_base + mi * 16 + ((lane >> 4) << 2);
        #pragma unroll
        for (int ni = 0; ni < 4; ++ni) {
            int col = n_base + ni * 16 + lr;
            float bv = bias ? bias[col] : 0.f;
            #pragma unroll
            for (int r = 0; r < 4; ++r) {
                int row = row0 + r;
                if (row < M) {
                    float x = acc[mi][ni][r] + bv;
                    if (ACT == 1) x = fmaxf(x, 0.f);
                    if (ACT == 2) x = 1.f / (1.f + __expf(-x));
                    if constexpr (std::is_same<OT, u16>::value)
                        C[(size_t)row * N + col] = f2bf(x);
                    else
                        C[(size_t)row * N + col] = x;
                }
            }
        }
    }
}

// ---------------------------------------------------------------------------
// Build X[r] = [ selfP[self_idx[r]] (256 bf16) | mean_f nbP[nb_idx[r*10+f]] ]
// One wave per row r. idx==nullptr means identity (r or r*10+f).
// ---------------------------------------------------------------------------
__global__ void build_x_k(u16* __restrict__ X, const u16* __restrict__ selfP,
                          const int* __restrict__ self_idx,
                          const u16* __restrict__ nbP,
                          const int* __restrict__ nb_idx, int R) {
    int w = (blockIdx.x * blockDim.x + threadIdx.x) >> 6;
    int lane = threadIdx.x & 63;
    if (w >= R) return;
    int c4 = lane * 4;
    int sr = self_idx ? self_idx[w] : w;
    ushort4 sv = *(const ushort4*)&selfP[(size_t)sr * 256 + c4];
    *(ushort4*)&X[(size_t)w * 512 + c4] = sv;

    float a0 = 0.f, a1 = 0.f, a2 = 0.f, a3 = 0.f;
    #pragma unroll
    for (int f = 0; f < 10; ++f) {
        int nr = nb_idx ? nb_idx[w * 10 + f] : w * 10 + f;
        ushort4 nv = *(const ushort4*)&nbP[(size_t)nr * 256 + c4];
        a0 += bf2f(nv.x); a1 += bf2f(nv.y); a2 += bf2f(nv.z); a3 += bf2f(nv.w);
    }
    ushort4 o;
    o.x = f2bf(a0 * 0.1f); o.y = f2bf(a1 * 0.1f);
    o.z = f2bf(a2 * 0.1f); o.w = f2bf(a3 * 0.1f);
    *(ushort4*)&X[(size_t)w * 512 + 256 + c4] = o;
}

// ---------------------------------------------------------------------------
// logits[b] = sum_k hu[b,k]*hi[b,k]*wlin[k] + blin    (one wave per b)
// ---------------------------------------------------------------------------
__global__ void logits_k(const float* __restrict__ hu, const float* __restrict__ hi,
                         const float* __restrict__ wlin, const float* __restrict__ blin,
                         float* __restrict__ out, int Bn) {
    int w = (blockIdx.x * blockDim.x + threadIdx.x) >> 6;
    int lane = threadIdx.x & 63;
    if (w >= Bn) return;
    float s = 0.f;
    #pragma unroll
    for (int k = lane; k < 128; k += 64)
        s += hu[(size_t)w * 128 + k] * hi[(size_t)w * 128 + k] * wlin[k];
    #pragma unroll
    for (int off = 32; off > 0; off >>= 1) s += __shfl_down(s, off, 64);
    if (lane == 0) out[w] = s + blin[0];
}

// ---------------------------------------------------------------------------
extern "C" void kernel_launch(void* const* d_in, const int* in_sizes, int n_in,
                              void* d_out, int out_size, void* d_ws, size_t ws_size,
                              hipStream_t stream) {
    const float* user_feat = (const float*)d_in[0];
    const float* item_feat = (const float*)d_in[1];
    const float* W_pu = (const float*)d_in[2];
    const float* b_pu = (const float*)d_in[3];
    const float* W_pi = (const float*)d_in[4];
    const float* b_pi = (const float*)d_in[5];
    const float* u_self0 = (const float*)d_in[6];
    const float* u_agg0 = (const float*)d_in[7];
    const float* u_self1 = (const float*)d_in[8];
    const float* u_agg1 = (const float*)d_in[9];
    const float* i_self0 = (const float*)d_in[10];
    const float* i_agg0 = (const float*)d_in[11];
    const float* i_self1 = (const float*)d_in[12];
    const float* i_agg1 = (const float*)d_in[13];
    const float* W_lin = (const float*)d_in[14];
    const float* b_lin = (const float*)d_in[15];
    const int* src_h0 = (const int*)d_in[16];
    const int* src_h1 = (const int*)d_in[17];
    const int* src_h2 = (const int*)d_in[18];
    const int* dst_h0 = (const int*)d_in[19];
    const int* dst_h1 = (const int*)d_in[20];
    const int* dst_h2 = (const int*)d_in[21];
    float* out = (float*)d_out;

    const int NU = 50000, NI = 100000, B = 4096, BF = 40960;

    char* ws = (char*)d_ws;
    size_t off = 0;
    auto alloc = [&](size_t bytes) -> void* {
        void* p = ws + off;
        off += (bytes + 255) & ~(size_t)255;
        return p;
    };
    u16* Pu  = (u16*)alloc((size_t)NU * 256 * 2);
    u16* Pi  = (u16*)alloc((size_t)NI * 256 * 2);
    u16* X1  = (u16*)alloc((size_t)BF * 512 * 2);
    u16* G1  = (u16*)alloc((size_t)BF * 256 * 2);
    u16* X0  = (u16*)alloc((size_t)B * 512 * 2);
    u16* G0  = (u16*)alloc((size_t)B * 256 * 2);
    u16* X2  = (u16*)alloc((size_t)B * 512 * 2);
    float* Hu = (float*)alloc((size_t)B * 128 * 4);
    float* Hi = (float*)alloc((size_t)B * 128 * 4);
    u16* WpuT = (u16*)alloc(256 * 512 * 2);
    u16* WpiT = (u16*)alloc(256 * 512 * 2);
    u16* W0uT = (u16*)alloc(256 * 512 * 2);
    u16* W0iT = (u16*)alloc(256 * 512 * 2);
    u16* W1uT = (u16*)alloc(128 * 512 * 2);
    u16* W1iT = (u16*)alloc(128 * 512 * 2);

    // --- weight prep: 6 transposed-concat bf16 layouts, one launch ---
    TCJobs tj;
    tj.A[0] = W_pu;    tj.Bm[0] = W_pu;    tj.out[0] = WpuT; tj.N[0] = 256; tj.Ka[0] = 512;
    tj.A[1] = W_pi;    tj.Bm[1] = W_pi;    tj.out[1] = WpiT; tj.N[1] = 256; tj.Ka[1] = 512;
    tj.A[2] = u_self0; tj.Bm[2] = u_agg0;  tj.out[2] = W0uT; tj.N[2] = 256; tj.Ka[2] = 256;
    tj.A[3] = i_self0; tj.Bm[3] = i_agg0;  tj.out[3] = W0iT; tj.N[3] = 256; tj.Ka[3] = 256;
    tj.A[4] = u_self1; tj.Bm[4] = u_agg1;  tj.out[4] = W1uT; tj.N[4] = 128; tj.Ka[4] = 256;
    tj.A[5] = i_self1; tj.Bm[5] = i_agg1;  tj.out[5] = W1iT; tj.N[5] = 128; tj.Ka[5] = 256;
    transcat6_k<<<dim3(512, 6), 256, 0, stream>>>(tj);

    // --- projections: P = sigmoid(feat @ W + b), bf16 out ---
    gemm_nl_k<float, 2, u16><<<dim3(4, (NU + 255) / 256), 256, 0, stream>>>(
        user_feat, WpuT, b_pu, Pu, NU, 256);
    gemm_nl_k<float, 2, u16><<<dim3(4, (NI + 255) / 256), 256, 0, stream>>>(
        item_feat, WpiT, b_pi, Pi, NI, 256);

    // --- user (src) side ---
    build_x_k<<<BF / 4, 256, 0, stream>>>(X1, Pi, src_h1, Pu, src_h2, BF);
    gemm_nl_k<u16, 1, u16><<<dim3(4, BF / 256), 256, 0, stream>>>(X1, W0uT, nullptr, G1, BF, 256);
    build_x_k<<<B / 4, 256, 0, stream>>>(X0, Pu, src_h0, Pi, src_h1, B);
    gemm_nl_k<u16, 1, u16><<<dim3(4, B / 256), 256, 0, stream>>>(X0, W0uT, nullptr, G0, B, 256);
    build_x_k<<<B / 4, 256, 0, stream>>>(X2, G0, nullptr, G1, nullptr, B);
    gemm_nl_k<u16, 0, float><<<dim3(2, B / 256), 256, 0, stream>>>(X2, W1uT, nullptr, Hu, B, 128);

    // --- item (dst) side ---
    build_x_k<<<BF / 4, 256, 0, stream>>>(X1, Pu, dst_h1, Pi, dst_h2, BF);
    gemm_nl_k<u16, 1, u16><<<dim3(4, BF / 256), 256, 0, stream>>>(X1, W0iT, nullptr, G1, BF, 256);
    build_x_k<<<B / 4, 256, 0, stream>>>(X0, Pi, dst_h0, Pu, dst_h1, B);
    gemm_nl_k<u16, 1, u16><<<dim3(4, B / 256), 256, 0, stream>>>(X0, W0iT, nullptr, G0, B, 256);
    build_x_k<<<B / 4, 256, 0, stream>>>(X2, G0, nullptr, G1, nullptr, B);
    gemm_nl_k<u16, 0, float><<<dim3(2, B / 256), 256, 0, stream>>>(X2, W1iT, nullptr, Hi, B, 128);

    // --- final logits ---
    logits_k<<<B / 4, 256, 0, stream>>>(Hu, Hi, W_lin, b_lin, out, B);
}

// Round 3
// 488.780 us; speedup vs baseline: 1.4304x; 1.4304x over previous
//
#include <hip/hip_runtime.h>
#include <type_traits>

typedef __attribute__((ext_vector_type(8))) short short8;
typedef __attribute__((ext_vector_type(4))) float f32x4;
typedef unsigned short u16;
typedef unsigned int u32;

typedef const __attribute__((address_space(1))) u32* gp1_t;
typedef __attribute__((address_space(3))) u32* lp3_t;

__device__ __forceinline__ float bf2f(u16 u) {
    union { unsigned int i; float f; } x; x.i = ((unsigned int)u) << 16; return x.f;
}
__device__ __forceinline__ u16 f2bf(float f) {
    union { float f; unsigned int i; } x; x.f = f;
    unsigned int r = x.i + 0x7FFFu + ((x.i >> 16) & 1u);
    return (u16)(r >> 16);
}
__device__ __forceinline__ short8 cvt8(float4 v0, float4 v1) {
    union { u16 u[8]; short8 s; } p;
    p.u[0] = f2bf(v0.x); p.u[1] = f2bf(v0.y); p.u[2] = f2bf(v0.z); p.u[3] = f2bf(v0.w);
    p.u[4] = f2bf(v1.x); p.u[5] = f2bf(v1.y); p.u[6] = f2bf(v1.z); p.u[7] = f2bf(v1.w);
    return p.s;
}
// async global->LDS, 16B per lane; lptr is the WAVE base (lane*16 added by HW)
__device__ __forceinline__ void gload_lds16(const void* g, void* l) {
    __builtin_amdgcn_global_load_lds((gp1_t)g, (lp3_t)l, 16, 0, 0);
}

// ---------------------------------------------------------------------------
// Fused weight transpose+concat+bf16: 6 jobs in one launch.
// out[n*512+k] = (k<Ka ? A[k][n] : B[k-Ka][n]); out is [N,512] bf16 W^T.
// ---------------------------------------------------------------------------
struct TCJobs {
    const float* A[6];
    const float* Bm[6];
    u16* out[6];
    int N[6];
    int Ka[6];
};

__global__ void transcat6_k(TCJobs j) {
    int jid = blockIdx.y;
    int i = blockIdx.x * 256 + threadIdx.x;
    int N = j.N[jid];
    if (i >= N * 512) return;
    int n = i >> 9, k = i & 511, Ka = j.Ka[jid];
    float v = (k < Ka) ? j.A[jid][k * N + n] : j.Bm[jid][(k - Ka) * N + n];
    j.out[jid][i] = f2bf(v);
}

// ---------------------------------------------------------------------------
// m97-style MFMA GEMM: C[M,N] = act(A[M,512] @ WT[N,512]^T + bias), N <= 256.
// Block = 128 rows x 256 cols, 8 waves (each 64x64), BK=64.
// Staging: global_load_lds_dwordx4 with PRE-SWIZZLED global source (rule #21),
// linear LDS dest; reads use matching ((row&7)<<4) byte-XOR -> conflict-free.
// AT=float: A staged raw f32, converted to bf16 at ds_read time (VALU is idle).
// ACT: 0 none, 1 relu, 2 sigmoid. OT = u16 (bf16) or float.
// ---------------------------------------------------------------------------
template <typename AT, int ACT, typename OT>
__global__ __launch_bounds__(512) void gemm_lds_k(const AT* __restrict__ A,
                                                  const u16* __restrict__ WT,
                                                  const float* __restrict__ bias,
                                                  OT* __restrict__ C, int M, int N) {
    const int K = 512;
    constexpr bool F32A = std::is_same<AT, float>::value;
    constexpr int AROWB = F32A ? 256 : 128;           // bytes per A-tile LDS row
    __shared__ __align__(1024) char As[128 * AROWB];  // 32 KB (f32) / 16 KB (bf16)
    __shared__ __align__(1024) char Bs[256 * 128];    // 32 KB
    const int t = threadIdx.x;
    const int lane = t & 63;
    const int wid = t >> 6;
    const int wr = wid >> 2, wc = wid & 3;            // wave tile: (wr*64, wc*64)
    const int lr = lane & 15;
    const int row_base = blockIdx.x * 128;

    f32x4 acc[4][4] = {};

    for (int kt = 0; kt < K; kt += 64) {
        // ---- stage B tile: 256 rows x 64 bf16 = 32 KB, 4 instr/wave ----
        #pragma unroll
        for (int i = 0; i < 4; ++i) {
            int slot = wid * 4 + i;
            int rl = slot * 8 + (lane >> 3);          // 0..255
            int sc = (lane & 7) ^ (rl & 7);           // source 16B-chunk (pre-swizzle)
            int nr = rl < N ? rl : N - 1;
            gload_lds16(&WT[(size_t)nr * K + kt + sc * 8], &Bs[slot * 1024]);
        }
        // ---- stage A tile: 128 rows x 64 elems ----
        if constexpr (F32A) {
            #pragma unroll
            for (int i = 0; i < 4; ++i) {             // 32 KB, 4 instr/wave
                int slot = wid * 4 + i;
                int rl = slot * 4 + (lane >> 4);      // 0..127
                int sc = (lane & 15) ^ (rl & 7);
                int gr = row_base + rl; if (gr >= M) gr = M - 1;
                gload_lds16(&A[(size_t)gr * K + kt + sc * 4], &As[slot * 1024]);
            }
        } else {
            #pragma unroll
            for (int i = 0; i < 2; ++i) {             // 16 KB, 2 instr/wave
                int slot = wid * 2 + i;
                int rl = slot * 8 + (lane >> 3);      // 0..127
                int sc = (lane & 7) ^ (rl & 7);
                int gr = row_base + rl; if (gr >= M) gr = M - 1;
                gload_lds16(&A[(size_t)gr * K + kt + sc * 8], &As[slot * 1024]);
            }
        }
        __syncthreads();   // compiler emits vmcnt(0) drain here (m97 structure)

        // ---- compute: 32 MFMA per wave per K-step ----
        #pragma unroll
        for (int ks = 0; ks < 2; ++ks) {
            const int g = ks * 4 + (lane >> 4);       // 8-elem k-group index (0..7)
            short8 a[4], b[4];
            #pragma unroll
            for (int ni = 0; ni < 4; ++ni) {
                int r = wc * 64 + ni * 16 + lr;
                b[ni] = *(const short8*)&Bs[(r * 128 + g * 16) ^ ((r & 7) << 4)];
            }
            #pragma unroll
            for (int mi = 0; mi < 4; ++mi) {
                int r = wr * 64 + mi * 16 + lr;
                if constexpr (F32A) {
                    float4 v0 = *(const float4*)&As[(r * 256 + (2 * g) * 16) ^ ((r & 7) << 4)];
                    float4 v1 = *(const float4*)&As[(r * 256 + (2 * g + 1) * 16) ^ ((r & 7) << 4)];
                    a[mi] = cvt8(v0, v1);
                } else {
                    a[mi] = *(const short8*)&As[(r * 128 + g * 16) ^ ((r & 7) << 4)];
                }
            }
            #pragma unroll
            for (int mi = 0; mi < 4; ++mi)
                #pragma unroll
                for (int ni = 0; ni < 4; ++ni)
                    acc[mi][ni] = __builtin_amdgcn_mfma_f32_16x16x32_bf16(
                        a[mi], b[ni], acc[mi][ni], 0, 0, 0);
        }
        __syncthreads();
    }

    // epilogue: C/D layout col=lane&15, row=(lane>>4)*4+reg  [m89 verified]
    #pragma unroll
    for (int mi = 0; mi < 4; ++mi) {
        int row0 = row_base + wr * 64 + mi * 16 + ((lane >> 4) << 2);
        #pragma unroll
        for (int ni = 0; ni < 4; ++ni) {
            int col = wc * 64 + ni * 16 + lr;
            if (col < N) {
                float bv = bias ? bias[col] : 0.f;
                #pragma unroll
                for (int r = 0; r < 4; ++r) {
                    int row = row0 + r;
                    if (row < M) {
                        float x = acc[mi][ni][r] + bv;
                        if (ACT == 1) x = fmaxf(x, 0.f);
                        if (ACT == 2) x = 1.f / (1.f + __expf(-x));
                        if constexpr (std::is_same<OT, u16>::value)
                            C[(size_t)row * N + col] = f2bf(x);
                        else
                            C[(size_t)row * N + col] = x;
                    }
                }
            }
        }
    }
}

// ---------------------------------------------------------------------------
// Build X[r] = [ selfP[self_idx[r]] (256 bf16) | mean_f nbP[nb_idx[r*10+f]] ]
// Half-wave (32 lanes) per row, 16 B/lane. idx==nullptr means identity.
// ---------------------------------------------------------------------------
__global__ void build_x_k(u16* __restrict__ X, const u16* __restrict__ selfP,
                          const int* __restrict__ self_idx,
                          const u16* __restrict__ nbP,
                          const int* __restrict__ nb_idx, int R) {
    int w = (blockIdx.x * blockDim.x + threadIdx.x) >> 5;   // row id
    int hl = threadIdx.x & 31;
    if (w >= R) return;
    int c8 = hl * 8;
    int sr = self_idx ? self_idx[w] : w;
    short8 sv = *(const short8*)&selfP[(size_t)sr * 256 + c8];
    *(short8*)&X[(size_t)w * 512 + c8] = sv;

    float s[8] = {};
    #pragma unroll
    for (int f = 0; f < 10; ++f) {
        int nr = nb_idx ? nb_idx[w * 10 + f] : w * 10 + f;
        short8 nv = *(const short8*)&nbP[(size_t)nr * 256 + c8];
        #pragma unroll
        for (int j = 0; j < 8; ++j) s[j] += bf2f((u16)nv[j]);
    }
    union { u16 u[8]; short8 v; } o;
    #pragma unroll
    for (int j = 0; j < 8; ++j) o.u[j] = f2bf(s[j] * 0.1f);
    *(short8*)&X[(size_t)w * 512 + 256 + c8] = o.v;
}

// ---------------------------------------------------------------------------
// logits[b] = sum_k hu[b,k]*hi[b,k]*wlin[k] + blin    (one wave per b)
// ---------------------------------------------------------------------------
__global__ void logits_k(const float* __restrict__ hu, const float* __restrict__ hi,
                         const float* __restrict__ wlin, const float* __restrict__ blin,
                         float* __restrict__ out, int Bn) {
    int w = (blockIdx.x * blockDim.x + threadIdx.x) >> 6;
    int lane = threadIdx.x & 63;
    if (w >= Bn) return;
    float s = 0.f;
    #pragma unroll
    for (int k = lane; k < 128; k += 64)
        s += hu[(size_t)w * 128 + k] * hi[(size_t)w * 128 + k] * wlin[k];
    #pragma unroll
    for (int off = 32; off > 0; off >>= 1) s += __shfl_down(s, off, 64);
    if (lane == 0) out[w] = s + blin[0];
}

// ---------------------------------------------------------------------------
extern "C" void kernel_launch(void* const* d_in, const int* in_sizes, int n_in,
                              void* d_out, int out_size, void* d_ws, size_t ws_size,
                              hipStream_t stream) {
    const float* user_feat = (const float*)d_in[0];
    const float* item_feat = (const float*)d_in[1];
    const float* W_pu = (const float*)d_in[2];
    const float* b_pu = (const float*)d_in[3];
    const float* W_pi = (const float*)d_in[4];
    const float* b_pi = (const float*)d_in[5];
    const float* u_self0 = (const float*)d_in[6];
    const float* u_agg0 = (const float*)d_in[7];
    const float* u_self1 = (const float*)d_in[8];
    const float* u_agg1 = (const float*)d_in[9];
    const float* i_self0 = (const float*)d_in[10];
    const float* i_agg0 = (const float*)d_in[11];
    const float* i_self1 = (const float*)d_in[12];
    const float* i_agg1 = (const float*)d_in[13];
    const float* W_lin = (const float*)d_in[14];
    const float* b_lin = (const float*)d_in[15];
    const int* src_h0 = (const int*)d_in[16];
    const int* src_h1 = (const int*)d_in[17];
    const int* src_h2 = (const int*)d_in[18];
    const int* dst_h0 = (const int*)d_in[19];
    const int* dst_h1 = (const int*)d_in[20];
    const int* dst_h2 = (const int*)d_in[21];
    float* out = (float*)d_out;

    const int NU = 50000, NI = 100000, B = 4096, BF = 40960;

    char* ws = (char*)d_ws;
    size_t off = 0;
    auto alloc = [&](size_t bytes) -> void* {
        void* p = ws + off;
        off += (bytes + 255) & ~(size_t)255;
        return p;
    };
    u16* Pu  = (u16*)alloc((size_t)NU * 256 * 2);
    u16* Pi  = (u16*)alloc((size_t)NI * 256 * 2);
    u16* X1  = (u16*)alloc((size_t)BF * 512 * 2);
    u16* G1  = (u16*)alloc((size_t)BF * 256 * 2);
    u16* X0  = (u16*)alloc((size_t)B * 512 * 2);
    u16* G0  = (u16*)alloc((size_t)B * 256 * 2);
    u16* X2  = (u16*)alloc((size_t)B * 512 * 2);
    float* Hu = (float*)alloc((size_t)B * 128 * 4);
    float* Hi = (float*)alloc((size_t)B * 128 * 4);
    u16* WpuT = (u16*)alloc(256 * 512 * 2);
    u16* WpiT = (u16*)alloc(256 * 512 * 2);
    u16* W0uT = (u16*)alloc(256 * 512 * 2);
    u16* W0iT = (u16*)alloc(256 * 512 * 2);
    u16* W1uT = (u16*)alloc(128 * 512 * 2);
    u16* W1iT = (u16*)alloc(128 * 512 * 2);

    // --- weight prep: 6 transposed-concat bf16 layouts, one launch ---
    TCJobs tj;
    tj.A[0] = W_pu;    tj.Bm[0] = W_pu;    tj.out[0] = WpuT; tj.N[0] = 256; tj.Ka[0] = 512;
    tj.A[1] = W_pi;    tj.Bm[1] = W_pi;    tj.out[1] = WpiT; tj.N[1] = 256; tj.Ka[1] = 512;
    tj.A[2] = u_self0; tj.Bm[2] = u_agg0;  tj.out[2] = W0uT; tj.N[2] = 256; tj.Ka[2] = 256;
    tj.A[3] = i_self0; tj.Bm[3] = i_agg0;  tj.out[3] = W0iT; tj.N[3] = 256; tj.Ka[3] = 256;
    tj.A[4] = u_self1; tj.Bm[4] = u_agg1;  tj.out[4] = W1uT; tj.N[4] = 128; tj.Ka[4] = 256;
    tj.A[5] = i_self1; tj.Bm[5] = i_agg1;  tj.out[5] = W1iT; tj.N[5] = 128; tj.Ka[5] = 256;
    transcat6_k<<<dim3(512, 6), 256, 0, stream>>>(tj);

    // --- projections: P = sigmoid(feat @ W + b), bf16 out ---
    gemm_lds_k<float, 2, u16><<<(NU + 127) / 128, 512, 0, stream>>>(
        user_feat, WpuT, b_pu, Pu, NU, 256);
    gemm_lds_k<float, 2, u16><<<(NI + 127) / 128, 512, 0, stream>>>(
        item_feat, WpiT, b_pi, Pi, NI, 256);

    // --- user (src) side ---
    build_x_k<<<BF / 8, 256, 0, stream>>>(X1, Pi, src_h1, Pu, src_h2, BF);
    gemm_lds_k<u16, 1, u16><<<BF / 128, 512, 0, stream>>>(X1, W0uT, nullptr, G1, BF, 256);
    build_x_k<<<B / 8, 256, 0, stream>>>(X0, Pu, src_h0, Pi, src_h1, B);
    gemm_lds_k<u16, 1, u16><<<B / 128, 512, 0, stream>>>(X0, W0uT, nullptr, G0, B, 256);
    build_x_k<<<B / 8, 256, 0, stream>>>(X2, G0, nullptr, G1, nullptr, B);
    gemm_lds_k<u16, 0, float><<<B / 128, 512, 0, stream>>>(X2, W1uT, nullptr, Hu, B, 128);

    // --- item (dst) side ---
    build_x_k<<<BF / 8, 256, 0, stream>>>(X1, Pu, dst_h1, Pi, dst_h2, BF);
    gemm_lds_k<u16, 1, u16><<<BF / 128, 512, 0, stream>>>(X1, W0iT, nullptr, G1, BF, 256);
    build_x_k<<<B / 8, 256, 0, stream>>>(X0, Pi, dst_h0, Pu, dst_h1, B);
    gemm_lds_k<u16, 1, u16><<<B / 128, 512, 0, stream>>>(X0, W0iT, nullptr, G0, B, 256);
    build_x_k<<<B / 8, 256, 0, stream>>>(X2, G0, nullptr, G1, nullptr, B);
    gemm_lds_k<u16, 0, float><<<B / 128, 512, 0, stream>>>(X2, W1iT, nullptr, Hi, B, 128);

    // --- final logits ---
    logits_k<<<B / 4, 256, 0, stream>>>(Hu, Hi, W_lin, b_lin, out, B);
}

// Round 4
// 451.283 us; speedup vs baseline: 1.5493x; 1.0831x over previous
//
#include <hip/hip_runtime.h>
#include <hip/hip_bf16.h>
#include <type_traits>

typedef __attribute__((ext_vector_type(8))) short short8;
typedef __attribute__((ext_vector_type(4))) float f32x4;
typedef unsigned short u16;
typedef unsigned int u32;

typedef const __attribute__((address_space(1))) u32* gp1_t;
typedef __attribute__((address_space(3))) u32* lp3_t;

__device__ __forceinline__ float bf2f(u16 u) {
    union { unsigned int i; float f; } x; x.i = ((unsigned int)u) << 16; return x.f;
}
// hardware RNE f32->bf16 (compiler packs pairs into v_cvt_pk_bf16_f32)
__device__ __forceinline__ u16 f2bf(float f) {
    union { __hip_bfloat16 h; u16 u; } c; c.h = __float2bfloat16(f); return c.u;
}
__device__ __forceinline__ short8 cvt8(float4 v0, float4 v1) {
    union { u16 u[8]; short8 s; } p;
    p.u[0] = f2bf(v0.x); p.u[1] = f2bf(v0.y); p.u[2] = f2bf(v0.z); p.u[3] = f2bf(v0.w);
    p.u[4] = f2bf(v1.x); p.u[5] = f2bf(v1.y); p.u[6] = f2bf(v1.z); p.u[7] = f2bf(v1.w);
    return p.s;
}
// async global->LDS, 16B per lane; LDS ptr is the WAVE base (lane*16 added by HW)
__device__ __forceinline__ void gload_lds16(const void* g, void* l) {
    __builtin_amdgcn_global_load_lds((gp1_t)g, (lp3_t)l, 16, 0, 0);
}

// ---------------------------------------------------------------------------
// Fused weight transpose+concat+bf16: 6 jobs in one launch.
// out[n*512+k] = (k<Ka ? A[k][n] : B[k-Ka][n]); out is [N,512] bf16 W^T.
// ---------------------------------------------------------------------------
struct TCJobs {
    const float* A[6];
    const float* Bm[6];
    u16* out[6];
    int N[6];
    int Ka[6];
};

__global__ void transcat6_k(TCJobs j) {
    int jid = blockIdx.y;
    int i = blockIdx.x * 256 + threadIdx.x;
    int N = j.N[jid];
    if (i >= N * 512) return;
    int n = i >> 9, k = i & 511, Ka = j.Ka[jid];
    float v = (k < Ka) ? j.A[jid][k * N + n] : j.Bm[jid][(k - Ka) * N + n];
    j.out[jid][i] = f2bf(v);
}

// ---------------------------------------------------------------------------
// 2-phase double-buffered MFMA GEMM (T3 minimum recipe):
//   prologue STAGE(0); barrier; loop { STAGE(t+1); COMPUTE(t); barrier; }
// C[M,N] = act(A[M,512] @ WT[N,512]^T + bias), N <= 256.
// Block = 128 rows x 256 cols, 8 waves (64x64 each), BK=64.
// Staging via global_load_lds_dwordx4, pre-swizzled global source (rule #21),
// linear LDS dest; ds_reads use the matching byte-XOR.
// AT=float: A staged raw f32, hw-converted to bf16 at ds_read time.
// ACT: 0 none, 1 relu, 2 sigmoid. OT = u16 (bf16) or float.
// ---------------------------------------------------------------------------
template <typename AT, int ACT, typename OT>
__global__ __launch_bounds__(512) void gemm_db_k(const AT* __restrict__ A,
                                                 const u16* __restrict__ WT,
                                                 const float* __restrict__ bias,
                                                 OT* __restrict__ C, int M, int N) {
    const int K = 512;
    constexpr bool F32A = std::is_same<AT, float>::value;
    constexpr int AROWB = F32A ? 256 : 128;             // bytes per A-tile LDS row
    __shared__ __align__(1024) char As[2][128 * AROWB]; // 2x32 KB (f32) / 2x16 KB
    __shared__ __align__(1024) char Bs[2][256 * 128];   // 2x32 KB
    const int t = threadIdx.x;
    const int lane = t & 63;
    const int wid = t >> 6;
    const int wr = wid >> 2, wc = wid & 3;              // wave tile: (wr*64, wc*64)
    const int lr = lane & 15;
    const int row_base = blockIdx.x * 128;

    f32x4 acc[4][4] = {};

    auto stage = [&](int kt, int pb) {
        char* bs = Bs[pb];
        #pragma unroll
        for (int i = 0; i < 4; ++i) {                   // B: 256 rows x 64 bf16
            int slot = wid * 4 + i;
            int rl = slot * 8 + (lane >> 3);            // 0..255
            int sc = (lane & 7) ^ (rl & 7);             // pre-swizzled source chunk
            int nr = rl < N ? rl : N - 1;
            gload_lds16(&WT[(size_t)nr * K + kt + sc * 8], &bs[slot * 1024]);
        }
        char* as = As[pb];
        if constexpr (F32A) {
            #pragma unroll
            for (int i = 0; i < 4; ++i) {               // A: 128 rows x 64 f32
                int slot = wid * 4 + i;
                int rl = slot * 4 + (lane >> 4);        // 0..127
                int sc = (lane & 15) ^ (rl & 7);
                int gr = row_base + rl; if (gr >= M) gr = M - 1;
                gload_lds16(&A[(size_t)gr * K + kt + sc * 4], &as[slot * 1024]);
            }
        } else {
            #pragma unroll
            for (int i = 0; i < 2; ++i) {               // A: 128 rows x 64 bf16
                int slot = wid * 2 + i;
                int rl = slot * 8 + (lane >> 3);        // 0..127
                int sc = (lane & 7) ^ (rl & 7);
                int gr = row_base + rl; if (gr >= M) gr = M - 1;
                gload_lds16(&A[(size_t)gr * K + kt + sc * 8], &as[slot * 1024]);
            }
        }
    };

    auto compute = [&](int pb) {
        const char* as = As[pb];
        const char* bs = Bs[pb];
        #pragma unroll
        for (int ks = 0; ks < 2; ++ks) {
            const int g = ks * 4 + (lane >> 4);         // 8-elem k-group (0..7)
            short8 a[4], b[4];
            #pragma unroll
            for (int ni = 0; ni < 4; ++ni) {
                int r = wc * 64 + ni * 16 + lr;
                b[ni] = *(const short8*)&bs[(r * 128 + g * 16) ^ ((r & 7) << 4)];
            }
            #pragma unroll
            for (int mi = 0; mi < 4; ++mi) {
                int r = wr * 64 + mi * 16 + lr;
                if constexpr (F32A) {
                    float4 v0 = *(const float4*)&as[(r * 256 + (2 * g) * 16) ^ ((r & 7) << 4)];
                    float4 v1 = *(const float4*)&as[(r * 256 + (2 * g + 1) * 16) ^ ((r & 7) << 4)];
                    a[mi] = cvt8(v0, v1);
                } else {
                    a[mi] = *(const short8*)&as[(r * 128 + g * 16) ^ ((r & 7) << 4)];
                }
            }
            #pragma unroll
            for (int mi = 0; mi < 4; ++mi)
                #pragma unroll
                for (int ni = 0; ni < 4; ++ni)
                    acc[mi][ni] = __builtin_amdgcn_mfma_f32_16x16x32_bf16(
                        a[mi], b[ni], acc[mi][ni], 0, 0, 0);
        }
    };

    // ---- 2-phase pipeline ----
    stage(0, 0);
    __syncthreads();                 // prologue drain (only full-latency stall)
    int cur = 0;
    for (int kt = 64; kt <= K; kt += 64) {
        if (kt < K) stage(kt, cur ^ 1);   // prefetch next tile (in flight over compute)
        compute(cur);
        __syncthreads();             // vmcnt(0) drain: prefetch had compute-span to land
        cur ^= 1;
    }

    // epilogue: C/D layout col=lane&15, row=(lane>>4)*4+reg  [m89 verified]
    #pragma unroll
    for (int mi = 0; mi < 4; ++mi) {
        int row0 = row_base + wr * 64 + mi * 16 + ((lane >> 4) << 2);
        #pragma unroll
        for (int ni = 0; ni < 4; ++ni) {
            int col = wc * 64 + ni * 16 + lr;
            if (col < N) {
                float bv = bias ? bias[col] : 0.f;
                #pragma unroll
                for (int r = 0; r < 4; ++r) {
                    int row = row0 + r;
                    if (row < M) {
                        float x = acc[mi][ni][r] + bv;
                        if (ACT == 1) x = fmaxf(x, 0.f);
                        if (ACT == 2) x = 1.f / (1.f + __expf(-x));
                        if constexpr (std::is_same<OT, u16>::value)
                            C[(size_t)row * N + col] = f2bf(x);
                        else
                            C[(size_t)row * N + col] = x;
                    }
                }
            }
        }
    }
}

// ---------------------------------------------------------------------------
// Build X[r] = [ selfP[self_idx[r]] (256 bf16) | mean_f nbP[nb_idx[r*10+f]] ]
// Half-wave (32 lanes) per row, 16 B/lane. idx==nullptr means identity.
// ---------------------------------------------------------------------------
__global__ void build_x_k(u16* __restrict__ X, const u16* __restrict__ selfP,
                          const int* __restrict__ self_idx,
                          const u16* __restrict__ nbP,
                          const int* __restrict__ nb_idx, int R) {
    int w = (blockIdx.x * blockDim.x + threadIdx.x) >> 5;   // row id
    int hl = threadIdx.x & 31;
    if (w >= R) return;
    int c8 = hl * 8;
    int sr = self_idx ? self_idx[w] : w;
    short8 sv = *(const short8*)&selfP[(size_t)sr * 256 + c8];
    *(short8*)&X[(size_t)w * 512 + c8] = sv;

    float s[8] = {};
    #pragma unroll
    for (int f = 0; f < 10; ++f) {
        int nr = nb_idx ? nb_idx[w * 10 + f] : w * 10 + f;
        short8 nv = *(const short8*)&nbP[(size_t)nr * 256 + c8];
        #pragma unroll
        for (int j = 0; j < 8; ++j) s[j] += bf2f((u16)nv[j]);
    }
    union { u16 u[8]; short8 v; } o;
    #pragma unroll
    for (int j = 0; j < 8; ++j) o.u[j] = f2bf(s[j] * 0.1f);
    *(short8*)&X[(size_t)w * 512 + 256 + c8] = o.v;
}

// ---------------------------------------------------------------------------
// logits[b] = sum_k hu[b,k]*hi[b,k]*wlin[k] + blin    (one wave per b)
// ---------------------------------------------------------------------------
__global__ void logits_k(const float* __restrict__ hu, const float* __restrict__ hi,
                         const float* __restrict__ wlin, const float* __restrict__ blin,
                         float* __restrict__ out, int Bn) {
    int w = (blockIdx.x * blockDim.x + threadIdx.x) >> 6;
    int lane = threadIdx.x & 63;
    if (w >= Bn) return;
    float s = 0.f;
    #pragma unroll
    for (int k = lane; k < 128; k += 64)
        s += hu[(size_t)w * 128 + k] * hi[(size_t)w * 128 + k] * wlin[k];
    #pragma unroll
    for (int off = 32; off > 0; off >>= 1) s += __shfl_down(s, off, 64);
    if (lane == 0) out[w] = s + blin[0];
}

// ---------------------------------------------------------------------------
extern "C" void kernel_launch(void* const* d_in, const int* in_sizes, int n_in,
                              void* d_out, int out_size, void* d_ws, size_t ws_size,
                              hipStream_t stream) {
    const float* user_feat = (const float*)d_in[0];
    const float* item_feat = (const float*)d_in[1];
    const float* W_pu = (const float*)d_in[2];
    const float* b_pu = (const float*)d_in[3];
    const float* W_pi = (const float*)d_in[4];
    const float* b_pi = (const float*)d_in[5];
    const float* u_self0 = (const float*)d_in[6];
    const float* u_agg0 = (const float*)d_in[7];
    const float* u_self1 = (const float*)d_in[8];
    const float* u_agg1 = (const float*)d_in[9];
    const float* i_self0 = (const float*)d_in[10];
    const float* i_agg0 = (const float*)d_in[11];
    const float* i_self1 = (const float*)d_in[12];
    const float* i_agg1 = (const float*)d_in[13];
    const float* W_lin = (const float*)d_in[14];
    const float* b_lin = (const float*)d_in[15];
    const int* src_h0 = (const int*)d_in[16];
    const int* src_h1 = (const int*)d_in[17];
    const int* src_h2 = (const int*)d_in[18];
    const int* dst_h0 = (const int*)d_in[19];
    const int* dst_h1 = (const int*)d_in[20];
    const int* dst_h2 = (const int*)d_in[21];
    float* out = (float*)d_out;

    const int NU = 50000, NI = 100000, B = 4096, BF = 40960;

    char* ws = (char*)d_ws;
    size_t off = 0;
    auto alloc = [&](size_t bytes) -> void* {
        void* p = ws + off;
        off += (bytes + 255) & ~(size_t)255;
        return p;
    };
    u16* Pu  = (u16*)alloc((size_t)NU * 256 * 2);
    u16* Pi  = (u16*)alloc((size_t)NI * 256 * 2);
    u16* X1  = (u16*)alloc((size_t)BF * 512 * 2);
    u16* G1  = (u16*)alloc((size_t)BF * 256 * 2);
    u16* X0  = (u16*)alloc((size_t)B * 512 * 2);
    u16* G0  = (u16*)alloc((size_t)B * 256 * 2);
    u16* X2  = (u16*)alloc((size_t)B * 512 * 2);
    float* Hu = (float*)alloc((size_t)B * 128 * 4);
    float* Hi = (float*)alloc((size_t)B * 128 * 4);
    u16* WpuT = (u16*)alloc(256 * 512 * 2);
    u16* WpiT = (u16*)alloc(256 * 512 * 2);
    u16* W0uT = (u16*)alloc(256 * 512 * 2);
    u16* W0iT = (u16*)alloc(256 * 512 * 2);
    u16* W1uT = (u16*)alloc(128 * 512 * 2);
    u16* W1iT = (u16*)alloc(128 * 512 * 2);

    // --- weight prep: 6 transposed-concat bf16 layouts, one launch ---
    TCJobs tj;
    tj.A[0] = W_pu;    tj.Bm[0] = W_pu;    tj.out[0] = WpuT; tj.N[0] = 256; tj.Ka[0] = 512;
    tj.A[1] = W_pi;    tj.Bm[1] = W_pi;    tj.out[1] = WpiT; tj.N[1] = 256; tj.Ka[1] = 512;
    tj.A[2] = u_self0; tj.Bm[2] = u_agg0;  tj.out[2] = W0uT; tj.N[2] = 256; tj.Ka[2] = 256;
    tj.A[3] = i_self0; tj.Bm[3] = i_agg0;  tj.out[3] = W0iT; tj.N[3] = 256; tj.Ka[3] = 256;
    tj.A[4] = u_self1; tj.Bm[4] = u_agg1;  tj.out[4] = W1uT; tj.N[4] = 128; tj.Ka[4] = 256;
    tj.A[5] = i_self1; tj.Bm[5] = i_agg1;  tj.out[5] = W1iT; tj.N[5] = 128; tj.Ka[5] = 256;
    transcat6_k<<<dim3(512, 6), 256, 0, stream>>>(tj);

    // --- projections: P = sigmoid(feat @ W + b), bf16 out ---
    gemm_db_k<float, 2, u16><<<(NU + 127) / 128, 512, 0, stream>>>(
        user_feat, WpuT, b_pu, Pu, NU, 256);
    gemm_db_k<float, 2, u16><<<(NI + 127) / 128, 512, 0, stream>>>(
        item_feat, WpiT, b_pi, Pi, NI, 256);

    // --- user (src) side ---
    build_x_k<<<BF / 8, 256, 0, stream>>>(X1, Pi, src_h1, Pu, src_h2, BF);
    gemm_db_k<u16, 1, u16><<<BF / 128, 512, 0, stream>>>(X1, W0uT, nullptr, G1, BF, 256);
    build_x_k<<<B / 8, 256, 0, stream>>>(X0, Pu, src_h0, Pi, src_h1, B);
    gemm_db_k<u16, 1, u16><<<B / 128, 512, 0, stream>>>(X0, W0uT, nullptr, G0, B, 256);
    build_x_k<<<B / 8, 256, 0, stream>>>(X2, G0, nullptr, G1, nullptr, B);
    gemm_db_k<u16, 0, float><<<B / 128, 512, 0, stream>>>(X2, W1uT, nullptr, Hu, B, 128);

    // --- item (dst) side ---
    build_x_k<<<BF / 8, 256, 0, stream>>>(X1, Pu, dst_h1, Pi, dst_h2, BF);
    gemm_db_k<u16, 1, u16><<<BF / 128, 512, 0, stream>>>(X1, W0iT, nullptr, G1, BF, 256);
    build_x_k<<<B / 8, 256, 0, stream>>>(X0, Pi, dst_h0, Pu, dst_h1, B);
    gemm_db_k<u16, 1, u16><<<B / 128, 512, 0, stream>>>(X0, W0iT, nullptr, G0, B, 256);
    build_x_k<<<B / 8, 256, 0, stream>>>(X2, G0, nullptr, G1, nullptr, B);
    gemm_db_k<u16, 0, float><<<B / 128, 512, 0, stream>>>(X2, W1iT, nullptr, Hi, B, 128);

    // --- final logits ---
    logits_k<<<B / 4, 256, 0, stream>>>(Hu, Hi, W_lin, b_lin, out, B);
}

// Round 5
// 393.677 us; speedup vs baseline: 1.7760x; 1.1463x over previous
//
#include <hip/hip_runtime.h>
#include <hip/hip_bf16.h>
#include <type_traits>

typedef __attribute__((ext_vector_type(8))) short short8;
typedef __attribute__((ext_vector_type(4))) float f32x4;
typedef unsigned short u16;
typedef unsigned int u32;

typedef const __attribute__((address_space(1))) u32* gp1_t;
typedef __attribute__((address_space(3))) u32* lp3_t;

__device__ __forceinline__ float bf2f(u16 u) {
    union { unsigned int i; float f; } x; x.i = ((unsigned int)u) << 16; return x.f;
}
// hardware RNE f32->bf16 (compiler packs pairs into v_cvt_pk_bf16_f32)
__device__ __forceinline__ u16 f2bf(float f) {
    union { __hip_bfloat16 h; u16 u; } c; c.h = __float2bfloat16(f); return c.u;
}
__device__ __forceinline__ short8 cvt8(float4 v0, float4 v1) {
    union { u16 u[8]; short8 s; } p;
    p.u[0] = f2bf(v0.x); p.u[1] = f2bf(v0.y); p.u[2] = f2bf(v0.z); p.u[3] = f2bf(v0.w);
    p.u[4] = f2bf(v1.x); p.u[5] = f2bf(v1.y); p.u[6] = f2bf(v1.z); p.u[7] = f2bf(v1.w);
    return p.s;
}
// async global->LDS, 16B per lane; LDS ptr is the WAVE base (lane*16 added by HW)
__device__ __forceinline__ void gload_lds16(const void* g, void* l) {
    __builtin_amdgcn_global_load_lds((gp1_t)g, (lp3_t)l, 16, 0, 0);
}

// ---------------------------------------------------------------------------
// Fused weight transpose+concat+bf16: 6 jobs in one launch.
// ---------------------------------------------------------------------------
struct TCJobs {
    const float* A[6];
    const float* Bm[6];
    u16* out[6];
    int N[6];
    int Ka[6];
};

__global__ void transcat6_k(TCJobs j) {
    int jid = blockIdx.y;
    int i = blockIdx.x * 256 + threadIdx.x;
    int N = j.N[jid];
    if (i >= N * 512) return;
    int n = i >> 9, k = i & 511, Ka = j.Ka[jid];
    float v = (k < Ka) ? j.A[jid][k * N + n] : j.Bm[jid][(k - Ka) * N + n];
    j.out[jid][i] = f2bf(v);
}

// ---------------------------------------------------------------------------
// m97-replica MFMA GEMM: C[M,N] = act(A[M,512] @ WT[N,512]^T + bias).
// 128x128 tile, 4 waves (64x64 each), BK=64, SINGLE-buffered 48/32 KB LDS ->
// ~3 blocks/CU; cross-block overlap hides the per-K-step vmcnt drain (m114).
// m204 bijective XCD-chunked swizzle: the nct col-tiles of one row-panel land
// on the same XCD so the A panel is fetched from HBM once, then L2-hit.
// Staging via global_load_lds_dwordx4, pre-swizzled global source (rule #21),
// linear LDS dest; ds_reads use the matching byte-XOR (2-way max = free).
// ---------------------------------------------------------------------------
template <typename AT, int ACT, typename OT>
__global__ __launch_bounds__(256, 3) void gemm97_k(const AT* __restrict__ A,
                                                   const u16* __restrict__ WT,
                                                   const float* __restrict__ bias,
                                                   OT* __restrict__ C, int M, int N) {
    const int K = 512;
    constexpr bool F32A = std::is_same<AT, float>::value;
    __shared__ __align__(1024) char As[F32A ? 32768 : 16384];
    __shared__ __align__(1024) char Bs[16384];
    const int t = threadIdx.x;
    const int lane = t & 63;
    const int wid = t >> 6;
    const int wr = wid >> 1, wc = wid & 1;   // wave tile: (wr*64, wc*64) in 128x128
    const int lr = lane & 15;

    // --- m204 bijective XCD-chunked tile swizzle ---
    const int nct = N >> 7;                  // col tiles (1 or 2)
    const int nwg = gridDim.x;
    const int p = blockIdx.x;
    const int q = nwg >> 3, rr = nwg & 7;
    const int xcd = p & 7, idx = p >> 3;
    const int L = (xcd < rr ? xcd * (q + 1) : rr * (q + 1) + (xcd - rr) * q) + idx;
    const int rt = L / nct, ct = L - rt * nct;
    const int row_base = rt * 128, col_base = ct * 128;

    f32x4 acc[4][4] = {};

    for (int kt = 0; kt < K; kt += 64) {
        // ---- stage B tile: 128 rows x 64 bf16 = 16 KB (4 instr/wave) ----
        #pragma unroll
        for (int i = 0; i < 4; ++i) {
            int slot = wid * 4 + i;                  // 0..15
            int rl = slot * 8 + (lane >> 3);         // 0..127
            int sc = (lane & 7) ^ (rl & 7);          // pre-swizzled source chunk
            gload_lds16(&WT[(size_t)(col_base + rl) * K + kt + sc * 8], &Bs[slot * 1024]);
        }
        // ---- stage A tile: 128 rows x 64 elems ----
        if constexpr (F32A) {
            #pragma unroll
            for (int i = 0; i < 8; ++i) {            // 32 KB, 8 instr/wave
                int slot = wid * 8 + i;              // 0..31
                int rl = slot * 4 + (lane >> 4);     // 0..127
                int sc = (lane & 15) ^ (rl & 7);
                int gr = row_base + rl; if (gr >= M) gr = M - 1;
                gload_lds16(&A[(size_t)gr * K + kt + sc * 4], &As[slot * 1024]);
            }
        } else {
            #pragma unroll
            for (int i = 0; i < 4; ++i) {            // 16 KB, 4 instr/wave
                int slot = wid * 4 + i;              // 0..15
                int rl = slot * 8 + (lane >> 3);     // 0..127
                int sc = (lane & 7) ^ (rl & 7);
                int gr = row_base + rl; if (gr >= M) gr = M - 1;
                gload_lds16(&A[(size_t)gr * K + kt + sc * 8], &As[slot * 1024]);
            }
        }
        __syncthreads();

        // ---- compute: 32 MFMA per wave per K-step ----
        #pragma unroll
        for (int ks = 0; ks < 2; ++ks) {
            const int g = ks * 4 + (lane >> 4);      // 8-elem k-group (0..7)
            short8 a[4], b[4];
            #pragma unroll
            for (int ni = 0; ni < 4; ++ni) {
                int r = wc * 64 + ni * 16 + lr;
                b[ni] = *(const short8*)&Bs[(r * 128 + g * 16) ^ ((r & 7) << 4)];
            }
            #pragma unroll
            for (int mi = 0; mi < 4; ++mi) {
                int r = wr * 64 + mi * 16 + lr;
                if constexpr (F32A) {
                    float4 v0 = *(const float4*)&As[(r * 256 + (2 * g) * 16) ^ ((r & 7) << 4)];
                    float4 v1 = *(const float4*)&As[(r * 256 + (2 * g + 1) * 16) ^ ((r & 7) << 4)];
                    a[mi] = cvt8(v0, v1);
                } else {
                    a[mi] = *(const short8*)&As[(r * 128 + g * 16) ^ ((r & 7) << 4)];
                }
            }
            #pragma unroll
            for (int mi = 0; mi < 4; ++mi)
                #pragma unroll
                for (int ni = 0; ni < 4; ++ni)
                    acc[mi][ni] = __builtin_amdgcn_mfma_f32_16x16x32_bf16(
                        a[mi], b[ni], acc[mi][ni], 0, 0, 0);
        }
        __syncthreads();
    }

    // epilogue: C/D layout col=lane&15, row=(lane>>4)*4+reg  [m89 verified]
    #pragma unroll
    for (int mi = 0; mi < 4; ++mi) {
        int row0 = row_base + wr * 64 + mi * 16 + ((lane >> 4) << 2);
        #pragma unroll
        for (int ni = 0; ni < 4; ++ni) {
            int col = col_base + wc * 64 + ni * 16 + lr;
            float bv = bias ? bias[col] : 0.f;
            #pragma unroll
            for (int r = 0; r < 4; ++r) {
                int row = row0 + r;
                if (row < M) {
                    float x = acc[mi][ni][r] + bv;
                    if (ACT == 1) x = fmaxf(x, 0.f);
                    if (ACT == 2) x = 1.f / (1.f + __expf(-x));
                    if constexpr (std::is_same<OT, u16>::value)
                        C[(size_t)row * N + col] = f2bf(x);
                    else
                        C[(size_t)row * N + col] = x;
                }
            }
        }
    }
}

// ---------------------------------------------------------------------------
// Build X[r] = [ selfP[self_idx[r]] (256 bf16) | mean_f nbP[nb_idx[r*10+f]] ]
// Half-wave (32 lanes) per row, 16 B/lane. idx==nullptr means identity.
// ---------------------------------------------------------------------------
__global__ void build_x_k(u16* __restrict__ X, const u16* __restrict__ selfP,
                          const int* __restrict__ self_idx,
                          const u16* __restrict__ nbP,
                          const int* __restrict__ nb_idx, int R) {
    int w = (blockIdx.x * blockDim.x + threadIdx.x) >> 5;   // row id
    int hl = threadIdx.x & 31;
    if (w >= R) return;
    int c8 = hl * 8;
    int sr = self_idx ? self_idx[w] : w;
    short8 sv = *(const short8*)&selfP[(size_t)sr * 256 + c8];
    *(short8*)&X[(size_t)w * 512 + c8] = sv;

    float s[8] = {};
    #pragma unroll
    for (int f = 0; f < 10; ++f) {
        int nr = nb_idx ? nb_idx[w * 10 + f] : w * 10 + f;
        short8 nv = *(const short8*)&nbP[(size_t)nr * 256 + c8];
        #pragma unroll
        for (int j = 0; j < 8; ++j) s[j] += bf2f((u16)nv[j]);
    }
    union { u16 u[8]; short8 v; } o;
    #pragma unroll
    for (int j = 0; j < 8; ++j) o.u[j] = f2bf(s[j] * 0.1f);
    *(short8*)&X[(size_t)w * 512 + 256 + c8] = o.v;
}

// ---------------------------------------------------------------------------
// logits[b] = sum_k hu[b,k]*hi[b,k]*wlin[k] + blin    (one wave per b)
// ---------------------------------------------------------------------------
__global__ void logits_k(const float* __restrict__ hu, const float* __restrict__ hi,
                         const float* __restrict__ wlin, const float* __restrict__ blin,
                         float* __restrict__ out, int Bn) {
    int w = (blockIdx.x * blockDim.x + threadIdx.x) >> 6;
    int lane = threadIdx.x & 63;
    if (w >= Bn) return;
    float s = 0.f;
    #pragma unroll
    for (int k = lane; k < 128; k += 64)
        s += hu[(size_t)w * 128 + k] * hi[(size_t)w * 128 + k] * wlin[k];
    #pragma unroll
    for (int off = 32; off > 0; off >>= 1) s += __shfl_down(s, off, 64);
    if (lane == 0) out[w] = s + blin[0];
}

// ---------------------------------------------------------------------------
extern "C" void kernel_launch(void* const* d_in, const int* in_sizes, int n_in,
                              void* d_out, int out_size, void* d_ws, size_t ws_size,
                              hipStream_t stream) {
    const float* user_feat = (const float*)d_in[0];
    const float* item_feat = (const float*)d_in[1];
    const float* W_pu = (const float*)d_in[2];
    const float* b_pu = (const float*)d_in[3];
    const float* W_pi = (const float*)d_in[4];
    const float* b_pi = (const float*)d_in[5];
    const float* u_self0 = (const float*)d_in[6];
    const float* u_agg0 = (const float*)d_in[7];
    const float* u_self1 = (const float*)d_in[8];
    const float* u_agg1 = (const float*)d_in[9];
    const float* i_self0 = (const float*)d_in[10];
    const float* i_agg0 = (const float*)d_in[11];
    const float* i_self1 = (const float*)d_in[12];
    const float* i_agg1 = (const float*)d_in[13];
    const float* W_lin = (const float*)d_in[14];
    const float* b_lin = (const float*)d_in[15];
    const int* src_h0 = (const int*)d_in[16];
    const int* src_h1 = (const int*)d_in[17];
    const int* src_h2 = (const int*)d_in[18];
    const int* dst_h0 = (const int*)d_in[19];
    const int* dst_h1 = (const int*)d_in[20];
    const int* dst_h2 = (const int*)d_in[21];
    float* out = (float*)d_out;

    const int NU = 50000, NI = 100000, B = 4096, BF = 40960;

    char* ws = (char*)d_ws;
    size_t off = 0;
    auto alloc = [&](size_t bytes) -> void* {
        void* p = ws + off;
        off += (bytes + 255) & ~(size_t)255;
        return p;
    };
    u16* Pu  = (u16*)alloc((size_t)NU * 256 * 2);
    u16* Pi  = (u16*)alloc((size_t)NI * 256 * 2);
    u16* X1  = (u16*)alloc((size_t)BF * 512 * 2);
    u16* G1  = (u16*)alloc((size_t)BF * 256 * 2);
    u16* X0  = (u16*)alloc((size_t)B * 512 * 2);
    u16* G0  = (u16*)alloc((size_t)B * 256 * 2);
    u16* X2  = (u16*)alloc((size_t)B * 512 * 2);
    float* Hu = (float*)alloc((size_t)B * 128 * 4);
    float* Hi = (float*)alloc((size_t)B * 128 * 4);
    u16* WpuT = (u16*)alloc(256 * 512 * 2);
    u16* WpiT = (u16*)alloc(256 * 512 * 2);
    u16* W0uT = (u16*)alloc(256 * 512 * 2);
    u16* W0iT = (u16*)alloc(256 * 512 * 2);
    u16* W1uT = (u16*)alloc(128 * 512 * 2);
    u16* W1iT = (u16*)alloc(128 * 512 * 2);

    // --- weight prep: 6 transposed-concat bf16 layouts, one launch ---
    TCJobs tj;
    tj.A[0] = W_pu;    tj.Bm[0] = W_pu;    tj.out[0] = WpuT; tj.N[0] = 256; tj.Ka[0] = 512;
    tj.A[1] = W_pi;    tj.Bm[1] = W_pi;    tj.out[1] = WpiT; tj.N[1] = 256; tj.Ka[1] = 512;
    tj.A[2] = u_self0; tj.Bm[2] = u_agg0;  tj.out[2] = W0uT; tj.N[2] = 256; tj.Ka[2] = 256;
    tj.A[3] = i_self0; tj.Bm[3] = i_agg0;  tj.out[3] = W0iT; tj.N[3] = 256; tj.Ka[3] = 256;
    tj.A[4] = u_self1; tj.Bm[4] = u_agg1;  tj.out[4] = W1uT; tj.N[4] = 128; tj.Ka[4] = 256;
    tj.A[5] = i_self1; tj.Bm[5] = i_agg1;  tj.out[5] = W1iT; tj.N[5] = 128; tj.Ka[5] = 256;
    transcat6_k<<<dim3(512, 6), 256, 0, stream>>>(tj);

    // --- projections: P = sigmoid(feat @ W + b), bf16 out ---
    gemm97_k<float, 2, u16><<<((NU + 127) / 128) * 2, 256, 0, stream>>>(
        user_feat, WpuT, b_pu, Pu, NU, 256);
    gemm97_k<float, 2, u16><<<((NI + 127) / 128) * 2, 256, 0, stream>>>(
        item_feat, WpiT, b_pi, Pi, NI, 256);

    // --- user (src) side ---
    build_x_k<<<BF / 8, 256, 0, stream>>>(X1, Pi, src_h1, Pu, src_h2, BF);
    gemm97_k<u16, 1, u16><<<(BF / 128) * 2, 256, 0, stream>>>(X1, W0uT, nullptr, G1, BF, 256);
    build_x_k<<<B / 8, 256, 0, stream>>>(X0, Pu, src_h0, Pi, src_h1, B);
    gemm97_k<u16, 1, u16><<<(B / 128) * 2, 256, 0, stream>>>(X0, W0uT, nullptr, G0, B, 256);
    build_x_k<<<B / 8, 256, 0, stream>>>(X2, G0, nullptr, G1, nullptr, B);
    gemm97_k<u16, 0, float><<<(B / 128), 256, 0, stream>>>(X2, W1uT, nullptr, Hu, B, 128);

    // --- item (dst) side ---
    build_x_k<<<BF / 8, 256, 0, stream>>>(X1, Pu, dst_h1, Pi, dst_h2, BF);
    gemm97_k<u16, 1, u16><<<(BF / 128) * 2, 256, 0, stream>>>(X1, W0iT, nullptr, G1, BF, 256);
    build_x_k<<<B / 8, 256, 0, stream>>>(X0, Pi, dst_h0, Pu, dst_h1, B);
    gemm97_k<u16, 1, u16><<<(B / 128) * 2, 256, 0, stream>>>(X0, W0iT, nullptr, G0, B, 256);
    build_x_k<<<B / 8, 256, 0, stream>>>(X2, G0, nullptr, G1, nullptr, B);
    gemm97_k<u16, 0, float><<<(B / 128), 256, 0, stream>>>(X2, W1iT, nullptr, Hi, B, 128);

    // --- final logits ---
    logits_k<<<B / 4, 256, 0, stream>>>(Hu, Hi, W_lin, b_lin, out, B);
}

// Round 6
// 309.504 us; speedup vs baseline: 2.2590x; 1.2720x over previous
//
#include <hip/hip_runtime.h>
#include <hip/hip_bf16.h>
#include <type_traits>

typedef __attribute__((ext_vector_type(8))) short short8;
typedef __attribute__((ext_vector_type(4))) float f32x4;
typedef unsigned short u16;
typedef unsigned int u32;

typedef const __attribute__((address_space(1))) u32* gp1_t;
typedef __attribute__((address_space(3))) u32* lp3_t;

__device__ __forceinline__ float bf2f(u16 u) {
    union { unsigned int i; float f; } x; x.i = ((unsigned int)u) << 16; return x.f;
}
// hardware RNE f32->bf16 (compiler packs pairs into v_cvt_pk_bf16_f32)
__device__ __forceinline__ u16 f2bf(float f) {
    union { __hip_bfloat16 h; u16 u; } c; c.h = __float2bfloat16(f); return c.u;
}
__device__ __forceinline__ short8 cvt8(float4 v0, float4 v1) {
    union { u16 u[8]; short8 s; } p;
    p.u[0] = f2bf(v0.x); p.u[1] = f2bf(v0.y); p.u[2] = f2bf(v0.z); p.u[3] = f2bf(v0.w);
    p.u[4] = f2bf(v1.x); p.u[5] = f2bf(v1.y); p.u[6] = f2bf(v1.z); p.u[7] = f2bf(v1.w);
    return p.s;
}
// async global->LDS, 16B per lane; LDS ptr is the WAVE base (lane*16 added by HW)
__device__ __forceinline__ void gload_lds16(const void* g, void* l) {
    __builtin_amdgcn_global_load_lds((gp1_t)g, (lp3_t)l, 16, 0, 0);
}

// ---------------------------------------------------------------------------
// Fused weight transpose+concat+bf16: 6 jobs in one launch.
// ---------------------------------------------------------------------------
struct TCJobs {
    const float* A[6];
    const float* Bm[6];
    u16* out[6];
    int N[6];
    int Ka[6];
};

__global__ void transcat6_k(TCJobs j) {
    int jid = blockIdx.y;
    int i = blockIdx.x * 256 + threadIdx.x;
    int N = j.N[jid];
    if (i >= N * 512) return;
    int n = i >> 9, k = i & 511, Ka = j.Ka[jid];
    float v = (k < Ka) ? j.A[jid][k * N + n] : j.Bm[jid][(k - Ka) * N + n];
    j.out[jid][i] = f2bf(v);
}

// ---------------------------------------------------------------------------
// Merged-job m97-style MFMA GEMM. Each 128x128 tile block picks its job from
// a runtime table (sorted toff). 4 waves, BK=64, single-buffered 32 KB LDS ->
// 4 blocks/CU; cross-block overlap hides the per-K-step vmcnt drain (m114).
// m204 bijective XCD-chunked swizzle over the merged grid keeps a row-panel's
// col-tiles on one XCD (A panel HBM-fetched once, then L2-hit).
// F32A: A-tile is reg-staged global->VGPR->bf16->swizzled ds_write (LDS stays
// 32 KB; cvt done once per element at stage time). bf16 A: async DMA staging
// with pre-swizzled global source (rule #21), linear LDS dest.
// ---------------------------------------------------------------------------
struct GJob {
    const void* A;      // [M,512] f32 or bf16
    const u16* WT;      // [N,512] bf16 (transposed-concat weights)
    const float* bias;  // or nullptr
    void* C;            // [M,N] bf16 or f32
    int M;
    int nct;            // col tiles; N = nct*128
    int toff;           // first tile index of this job (ascending)
};
struct GJobs4 { GJob j[4]; };

template <int NJ, bool F32A, int ACT, bool OF32>
__global__ __launch_bounds__(256, 4) void gemm_k(GJobs4 js) {
    const int K = 512;
    __shared__ __align__(1024) char As[16384];
    __shared__ __align__(1024) char Bs[16384];
    const int t = threadIdx.x;
    const int lane = t & 63;
    const int wid = t >> 6;
    const int wr = wid >> 1, wc = wid & 1;   // wave tile: (wr*64, wc*64)
    const int lr = lane & 15;

    // m204 bijective XCD-chunked tile swizzle over the merged grid
    const int nwg = gridDim.x, p = blockIdx.x;
    const int q = nwg >> 3, rr = nwg & 7;
    const int xcd = p & 7, idx = p >> 3;
    const int L = (xcd < rr ? xcd * (q + 1) : rr * (q + 1) + (xcd - rr) * q) + idx;

    // job select (NJ small, table sorted by toff)
    GJob jb = js.j[0];
    #pragma unroll
    for (int k = 1; k < NJ; ++k) if (L >= js.j[k].toff) jb = js.j[k];
    const int tl = L - jb.toff;
    const int rt = (jb.nct == 2) ? (tl >> 1) : tl;
    const int ct = (jb.nct == 2) ? (tl & 1) : 0;
    const int row_base = rt * 128, col_base = ct * 128;
    const int M = jb.M, N = jb.nct << 7;

    f32x4 acc[4][4] = {};

    for (int kt = 0; kt < K; kt += 64) {
        // ---- stage B tile: 128 rows x 64 bf16 = 16 KB (async DMA, 4/wave) ----
        #pragma unroll
        for (int i = 0; i < 4; ++i) {
            int slot = wid * 4 + i;                  // 0..15
            int rl = slot * 8 + (lane >> 3);         // 0..127
            int sc = (lane & 7) ^ (rl & 7);          // pre-swizzled source chunk
            gload_lds16(&jb.WT[(size_t)(col_base + rl) * K + kt + sc * 8], &Bs[slot * 1024]);
        }
        // ---- stage A tile: 128 rows x 64 bf16 = 16 KB ----
        if constexpr (F32A) {
            const float* Af = (const float*)jb.A;
            #pragma unroll
            for (int i = 0; i < 4; ++i) {            // reg-stage + cvt + swizzled write
                int c = i * 256 + t;                 // chunk 0..1023 (8/row)
                int row = c >> 3, cc = c & 7;
                int gr = row_base + row; if (gr >= M) gr = M - 1;
                const float* src = &Af[(size_t)gr * K + kt + cc * 8];
                float4 v0 = *(const float4*)src;
                float4 v1 = *(const float4*)(src + 4);
                *(short8*)&As[(row * 128 + cc * 16) ^ ((row & 7) << 4)] = cvt8(v0, v1);
            }
        } else {
            const u16* Ab = (const u16*)jb.A;
            #pragma unroll
            for (int i = 0; i < 4; ++i) {
                int slot = wid * 4 + i;
                int rl = slot * 8 + (lane >> 3);
                int sc = (lane & 7) ^ (rl & 7);
                int gr = row_base + rl; if (gr >= M) gr = M - 1;
                gload_lds16(&Ab[(size_t)gr * K + kt + sc * 8], &As[slot * 1024]);
            }
        }
        __syncthreads();

        // ---- compute: 32 MFMA per wave per K-step ----
        #pragma unroll
        for (int ks = 0; ks < 2; ++ks) {
            const int g = ks * 4 + (lane >> 4);      // 8-elem k-group (0..7)
            short8 a[4], b[4];
            #pragma unroll
            for (int ni = 0; ni < 4; ++ni) {
                int r = wc * 64 + ni * 16 + lr;
                b[ni] = *(const short8*)&Bs[(r * 128 + g * 16) ^ ((r & 7) << 4)];
            }
            #pragma unroll
            for (int mi = 0; mi < 4; ++mi) {
                int r = wr * 64 + mi * 16 + lr;
                a[mi] = *(const short8*)&As[(r * 128 + g * 16) ^ ((r & 7) << 4)];
            }
            #pragma unroll
            for (int mi = 0; mi < 4; ++mi)
                #pragma unroll
                for (int ni = 0; ni < 4; ++ni)
                    acc[mi][ni] = __builtin_amdgcn_mfma_f32_16x16x32_bf16(
                        a[mi], b[ni], acc[mi][ni], 0, 0, 0);
        }
        __syncthreads();
    }

    // epilogue: C/D layout col=lane&15, row=(lane>>4)*4+reg  [m89 verified]
    #pragma unroll
    for (int mi = 0; mi < 4; ++mi) {
        int row0 = row_base + wr * 64 + mi * 16 + ((lane >> 4) << 2);
        #pragma unroll
        for (int ni = 0; ni < 4; ++ni) {
            int col = col_base + wc * 64 + ni * 16 + lr;
            float bv = jb.bias ? jb.bias[col] : 0.f;
            #pragma unroll
            for (int r = 0; r < 4; ++r) {
                int row = row0 + r;
                if (row < M) {
                    float x = acc[mi][ni][r] + bv;
                    if (ACT == 1) x = fmaxf(x, 0.f);
                    if (ACT == 2) x = 1.f / (1.f + __expf(-x));
                    if constexpr (OF32)
                        ((float*)jb.C)[(size_t)row * N + col] = x;
                    else
                        ((u16*)jb.C)[(size_t)row * N + col] = f2bf(x);
                }
            }
        }
    }
}

// ---------------------------------------------------------------------------
// Merged build_x: X[r] = [ selfP[sidx[r]] (256 bf16) | mean_f nbP[nidx[r*10+f]] ]
// Half-wave (32 lanes) per row, 16 B/lane. null idx means identity.
// ---------------------------------------------------------------------------
struct BJob {
    u16* X;
    const u16* selfP;
    const int* sidx;
    const u16* nbP;
    const int* nidx;
    int roff;           // first global row of this job (ascending)
};
struct BJobs4 { BJob j[4]; };

template <int NJ>
__global__ void build_xm_k(BJobs4 bj, int total) {
    int gw = (int)((blockIdx.x * blockDim.x + threadIdx.x) >> 5);
    int hl = threadIdx.x & 31;
    if (gw >= total) return;
    BJob jb = bj.j[0];
    #pragma unroll
    for (int k = 1; k < NJ; ++k) if (gw >= bj.j[k].roff) jb = bj.j[k];
    int r = gw - jb.roff;

    int c8 = hl * 8;
    int sr = jb.sidx ? jb.sidx[r] : r;
    short8 sv = *(const short8*)&jb.selfP[(size_t)sr * 256 + c8];
    *(short8*)&jb.X[(size_t)r * 512 + c8] = sv;

    float s[8] = {};
    #pragma unroll
    for (int f = 0; f < 10; ++f) {
        int nr = jb.nidx ? jb.nidx[r * 10 + f] : r * 10 + f;
        short8 nv = *(const short8*)&jb.nbP[(size_t)nr * 256 + c8];
        #pragma unroll
        for (int jj = 0; jj < 8; ++jj) s[jj] += bf2f((u16)nv[jj]);
    }
    union { u16 u[8]; short8 v; } o;
    #pragma unroll
    for (int jj = 0; jj < 8; ++jj) o.u[jj] = f2bf(s[jj] * 0.1f);
    *(short8*)&jb.X[(size_t)r * 512 + 256 + c8] = o.v;
}

// ---------------------------------------------------------------------------
// logits[b] = sum_k hu[b,k]*hi[b,k]*wlin[k] + blin    (one wave per b)
// ---------------------------------------------------------------------------
__global__ void logits_k(const float* __restrict__ hu, const float* __restrict__ hi,
                         const float* __restrict__ wlin, const float* __restrict__ blin,
                         float* __restrict__ out, int Bn) {
    int w = (blockIdx.x * blockDim.x + threadIdx.x) >> 6;
    int lane = threadIdx.x & 63;
    if (w >= Bn) return;
    float s = 0.f;
    #pragma unroll
    for (int k = lane; k < 128; k += 64)
        s += hu[(size_t)w * 128 + k] * hi[(size_t)w * 128 + k] * wlin[k];
    #pragma unroll
    for (int off = 32; off > 0; off >>= 1) s += __shfl_down(s, off, 64);
    if (lane == 0) out[w] = s + blin[0];
}

// ---------------------------------------------------------------------------
extern "C" void kernel_launch(void* const* d_in, const int* in_sizes, int n_in,
                              void* d_out, int out_size, void* d_ws, size_t ws_size,
                              hipStream_t stream) {
    const float* user_feat = (const float*)d_in[0];
    const float* item_feat = (const float*)d_in[1];
    const float* W_pu = (const float*)d_in[2];
    const float* b_pu = (const float*)d_in[3];
    const float* W_pi = (const float*)d_in[4];
    const float* b_pi = (const float*)d_in[5];
    const float* u_self0 = (const float*)d_in[6];
    const float* u_agg0 = (const float*)d_in[7];
    const float* u_self1 = (const float*)d_in[8];
    const float* u_agg1 = (const float*)d_in[9];
    const float* i_self0 = (const float*)d_in[10];
    const float* i_agg0 = (const float*)d_in[11];
    const float* i_self1 = (const float*)d_in[12];
    const float* i_agg1 = (const float*)d_in[13];
    const float* W_lin = (const float*)d_in[14];
    const float* b_lin = (const float*)d_in[15];
    const int* src_h0 = (const int*)d_in[16];
    const int* src_h1 = (const int*)d_in[17];
    const int* src_h2 = (const int*)d_in[18];
    const int* dst_h0 = (const int*)d_in[19];
    const int* dst_h1 = (const int*)d_in[20];
    const int* dst_h2 = (const int*)d_in[21];
    float* out = (float*)d_out;

    const int NU = 50000, NI = 100000, B = 4096, BF = 40960;

    char* ws = (char*)d_ws;
    size_t off = 0;
    auto alloc = [&](size_t bytes) -> void* {
        void* p = ws + off;
        off += (bytes + 255) & ~(size_t)255;
        return p;
    };
    u16* Pu   = (u16*)alloc((size_t)NU * 256 * 2);
    u16* Pi   = (u16*)alloc((size_t)NI * 256 * 2);
    u16* X1a  = (u16*)alloc((size_t)BF * 512 * 2);
    u16* X1b  = (u16*)alloc((size_t)BF * 512 * 2);
    u16* G1a  = (u16*)alloc((size_t)BF * 256 * 2);
    u16* G1b  = (u16*)alloc((size_t)BF * 256 * 2);
    u16* X0a  = (u16*)alloc((size_t)B * 512 * 2);
    u16* X0b  = (u16*)alloc((size_t)B * 512 * 2);
    u16* G0a  = (u16*)alloc((size_t)B * 256 * 2);
    u16* G0b  = (u16*)alloc((size_t)B * 256 * 2);
    u16* X2a  = (u16*)alloc((size_t)B * 512 * 2);
    u16* X2b  = (u16*)alloc((size_t)B * 512 * 2);
    float* Hu = (float*)alloc((size_t)B * 128 * 4);
    float* Hi = (float*)alloc((size_t)B * 128 * 4);
    u16* WpuT = (u16*)alloc(256 * 512 * 2);
    u16* WpiT = (u16*)alloc(256 * 512 * 2);
    u16* W0uT = (u16*)alloc(256 * 512 * 2);
    u16* W0iT = (u16*)alloc(256 * 512 * 2);
    u16* W1uT = (u16*)alloc(128 * 512 * 2);
    u16* W1iT = (u16*)alloc(128 * 512 * 2);

    // --- 1. weight prep: 6 transposed-concat bf16 layouts, one launch ---
    TCJobs tj;
    tj.A[0] = W_pu;    tj.Bm[0] = W_pu;    tj.out[0] = WpuT; tj.N[0] = 256; tj.Ka[0] = 512;
    tj.A[1] = W_pi;    tj.Bm[1] = W_pi;    tj.out[1] = WpiT; tj.N[1] = 256; tj.Ka[1] = 512;
    tj.A[2] = u_self0; tj.Bm[2] = u_agg0;  tj.out[2] = W0uT; tj.N[2] = 256; tj.Ka[2] = 256;
    tj.A[3] = i_self0; tj.Bm[3] = i_agg0;  tj.out[3] = W0iT; tj.N[3] = 256; tj.Ka[3] = 256;
    tj.A[4] = u_self1; tj.Bm[4] = u_agg1;  tj.out[4] = W1uT; tj.N[4] = 128; tj.Ka[4] = 256;
    tj.A[5] = i_self1; tj.Bm[5] = i_agg1;  tj.out[5] = W1iT; tj.N[5] = 128; tj.Ka[5] = 256;
    transcat6_k<<<dim3(512, 6), 256, 0, stream>>>(tj);

    // --- 2. both projections, one launch: P = sigmoid(feat @ W + b) ---
    const int ptu = ((NU + 127) / 128) * 2;          // 782
    const int pti = ((NI + 127) / 128) * 2;          // 1564
    GJobs4 pj;
    pj.j[0] = {user_feat, WpuT, b_pu, Pu, NU, 2, 0};
    pj.j[1] = {item_feat, WpiT, b_pi, Pi, NI, 2, ptu};
    pj.j[2] = pj.j[1]; pj.j[3] = pj.j[1];
    gemm_k<2, true, 2, false><<<ptu + pti, 256, 0, stream>>>(pj);

    // --- 3. all four gather/mean builds, one launch ---
    BJobs4 b1;
    b1.j[0] = {X1a, Pi, src_h1, Pu, src_h2, 0};
    b1.j[1] = {X1b, Pu, dst_h1, Pi, dst_h2, BF};
    b1.j[2] = {X0a, Pu, src_h0, Pi, src_h1, 2 * BF};
    b1.j[3] = {X0b, Pi, dst_h0, Pu, dst_h1, 2 * BF + B};
    const int tot1 = 2 * BF + 2 * B;                 // 90112
    build_xm_k<4><<<tot1 / 8, 256, 0, stream>>>(b1, tot1);

    // --- 4. all four SAGE layer-0 GEMMs (relu, bf16 out), one launch ---
    GJobs4 sj;
    sj.j[0] = {X1a, W0uT, nullptr, G1a, BF, 2, 0};
    sj.j[1] = {X1b, W0iT, nullptr, G1b, BF, 2, 640};
    sj.j[2] = {X0a, W0uT, nullptr, G0a, B, 2, 1280};
    sj.j[3] = {X0b, W0iT, nullptr, G0b, B, 2, 1344};
    gemm_k<4, false, 1, false><<<1408, 256, 0, stream>>>(sj);

    // --- 5. hop-0 concat builds (identity indices), one launch ---
    BJobs4 b2;
    b2.j[0] = {X2a, G0a, nullptr, G1a, nullptr, 0};
    b2.j[1] = {X2b, G0b, nullptr, G1b, nullptr, B};
    b2.j[2] = b2.j[1]; b2.j[3] = b2.j[1];
    build_xm_k<2><<<(2 * B) / 8, 256, 0, stream>>>(b2, 2 * B);

    // --- 6. both final GEMMs (no act, f32 out), one launch ---
    GJobs4 fj;
    fj.j[0] = {X2a, W1uT, nullptr, Hu, B, 1, 0};
    fj.j[1] = {X2b, W1iT, nullptr, Hi, B, 1, 32};
    fj.j[2] = fj.j[1]; fj.j[3] = fj.j[1];
    gemm_k<2, false, 0, true><<<64, 256, 0, stream>>>(fj);

    // --- 7. final logits ---
    logits_k<<<B / 4, 256, 0, stream>>>(Hu, Hi, W_lin, b_lin, out, B);
}

// Round 7
// 307.028 us; speedup vs baseline: 2.2772x; 1.0081x over previous
//
#include <hip/hip_runtime.h>
#include <hip/hip_bf16.h>
#include <type_traits>

typedef __attribute__((ext_vector_type(8))) short short8;
typedef __attribute__((ext_vector_type(4))) float f32x4;
typedef unsigned short u16;
typedef unsigned int u32;

typedef const __attribute__((address_space(1))) u32* gp1_t;
typedef __attribute__((address_space(3))) u32* lp3_t;

__device__ __forceinline__ float bf2f(u16 u) {
    union { unsigned int i; float f; } x; x.i = ((unsigned int)u) << 16; return x.f;
}
// hardware RNE f32->bf16 (compiler packs pairs into v_cvt_pk_bf16_f32)
__device__ __forceinline__ u16 f2bf(float f) {
    union { __hip_bfloat16 h; u16 u; } c; c.h = __float2bfloat16(f); return c.u;
}
__device__ __forceinline__ short8 cvt8(float4 v0, float4 v1) {
    union { u16 u[8]; short8 s; } p;
    p.u[0] = f2bf(v0.x); p.u[1] = f2bf(v0.y); p.u[2] = f2bf(v0.z); p.u[3] = f2bf(v0.w);
    p.u[4] = f2bf(v1.x); p.u[5] = f2bf(v1.y); p.u[6] = f2bf(v1.z); p.u[7] = f2bf(v1.w);
    return p.s;
}
// async global->LDS, 16B per lane; LDS ptr is the WAVE base (lane*16 added by HW)
__device__ __forceinline__ void gload_lds16(const void* g, void* l) {
    __builtin_amdgcn_global_load_lds((gp1_t)g, (lp3_t)l, 16, 0, 0);
}

// ---------------------------------------------------------------------------
// Fused weight transpose+concat+bf16: 6 jobs in one launch.
// ---------------------------------------------------------------------------
struct TCJobs {
    const float* A[6];
    const float* Bm[6];
    u16* out[6];
    int N[6];
    int Ka[6];
};

__global__ void transcat6_k(TCJobs j) {
    int jid = blockIdx.y;
    int i = blockIdx.x * 256 + threadIdx.x;
    int N = j.N[jid];
    if (i >= N * 512) return;
    int n = i >> 9, k = i & 511, Ka = j.Ka[jid];
    float v = (k < Ka) ? j.A[jid][k * N + n] : j.Bm[jid][(k - Ka) * N + n];
    j.out[jid][i] = f2bf(v);
}

// ---------------------------------------------------------------------------
// Merged-job MFMA GEMM, BK=32, full-DMA staging.
// 128x128 tile, 4 waves (64x64 each), single-buffered LDS:
//   f32 A: 16 KB (XOR-involution chunk swizzle, pre-swizzled DMA source)
//   bf16 A / B: 8 KB each, LINEAR (64-B rows -> natural 2-way conflicts, free)
// 24 KB (f32) / 16 KB (bf16) LDS -> 4 blocks/CU; block staggering covers the
// ~900-cy HBM latency (m114); all tile loads are back-to-back async DMA.
// m204 bijective XCD-chunked swizzle keeps a row-panel's col-tiles on one XCD.
// ---------------------------------------------------------------------------
struct GJob {
    const void* A;      // [M,512] f32 or bf16
    const u16* WT;      // [N,512] bf16 (transposed-concat weights)
    const float* bias;  // or nullptr
    void* C;            // [M,N] bf16 or f32
    int M;
    int nct;            // col tiles; N = nct*128
    int toff;           // first tile index of this job (ascending)
};
struct GJobs4 { GJob j[4]; };

template <int NJ, bool F32A, int ACT, bool OF32>
__global__ __launch_bounds__(256, 4) void gemm_k(GJobs4 js) {
    const int K = 512;
    __shared__ __align__(1024) char As[F32A ? 16384 : 8192];
    __shared__ __align__(1024) char Bs[8192];
    const int t = threadIdx.x;
    const int lane = t & 63;
    const int wid = t >> 6;
    const int wr = wid >> 1, wc = wid & 1;   // wave tile: (wr*64, wc*64)
    const int lr = lane & 15;

    // m204 bijective XCD-chunked tile swizzle over the merged grid
    const int nwg = gridDim.x, p = blockIdx.x;
    const int q = nwg >> 3, rr = nwg & 7;
    const int xcd = p & 7, idx = p >> 3;
    const int L = (xcd < rr ? xcd * (q + 1) : rr * (q + 1) + (xcd - rr) * q) + idx;

    // job select (NJ small, table sorted by toff)
    GJob jb = js.j[0];
    #pragma unroll
    for (int k = 1; k < NJ; ++k) if (L >= js.j[k].toff) jb = js.j[k];
    const int tl = L - jb.toff;
    const int rt = (jb.nct == 2) ? (tl >> 1) : tl;
    const int ct = (jb.nct == 2) ? (tl & 1) : 0;
    const int row_base = rt * 128, col_base = ct * 128;
    const int M = jb.M, N = jb.nct << 7;

    f32x4 acc[4][4] = {};

    for (int kt = 0; kt < K; kt += 32) {
        // ---- stage B tile: 128 rows x 32 bf16 = 8 KB, linear (2 DMA/wave) ----
        #pragma unroll
        for (int i = 0; i < 2; ++i) {
            int slot = wid * 2 + i;                  // 0..7, 16 rows each
            int rl = slot * 16 + (lane >> 2);        // 0..127
            int cc = lane & 3;                       // 16-B chunk of 4
            gload_lds16(&jb.WT[(size_t)(col_base + rl) * K + kt + cc * 8], &Bs[slot * 1024]);
        }
        // ---- stage A tile: 128 rows x 32 elems ----
        if constexpr (F32A) {
            #pragma unroll
            for (int i = 0; i < 4; ++i) {            // 16 KB, 4 DMA/wave, swizzled src
                int slot = wid * 4 + i;              // 0..15, 8 rows each
                int rl = slot * 8 + (lane >> 3);     // 0..127
                int sc = (lane & 7) ^ (rl & 7);      // involution chunk swizzle
                int gr = row_base + rl; if (gr >= M) gr = M - 1;
                gload_lds16(&((const float*)jb.A)[(size_t)gr * K + kt + sc * 4],
                            &As[slot * 1024]);
            }
        } else {
            #pragma unroll
            for (int i = 0; i < 2; ++i) {            // 8 KB, 2 DMA/wave, linear
                int slot = wid * 2 + i;
                int rl = slot * 16 + (lane >> 2);
                int cc = lane & 3;
                int gr = row_base + rl; if (gr >= M) gr = M - 1;
                gload_lds16(&((const u16*)jb.A)[(size_t)gr * K + kt + cc * 8],
                            &As[slot * 1024]);
            }
        }
        __syncthreads();

        // ---- compute: 16 MFMA per wave per K-step ----
        {
            const int g = lane >> 4;                 // 8-elem k-group (0..3)
            short8 a[4], b[4];
            #pragma unroll
            for (int ni = 0; ni < 4; ++ni) {
                int r = wc * 64 + ni * 16 + lr;
                b[ni] = *(const short8*)&Bs[r * 64 + g * 16];
            }
            #pragma unroll
            for (int mi = 0; mi < 4; ++mi) {
                int r = wr * 64 + mi * 16 + lr;
                if constexpr (F32A) {
                    float4 v0 = *(const float4*)&As[r * 128 + ((2 * g) ^ (r & 7)) * 16];
                    float4 v1 = *(const float4*)&As[r * 128 + ((2 * g + 1) ^ (r & 7)) * 16];
                    a[mi] = cvt8(v0, v1);
                } else {
                    a[mi] = *(const short8*)&As[r * 64 + g * 16];
                }
            }
            #pragma unroll
            for (int mi = 0; mi < 4; ++mi)
                #pragma unroll
                for (int ni = 0; ni < 4; ++ni)
                    acc[mi][ni] = __builtin_amdgcn_mfma_f32_16x16x32_bf16(
                        a[mi], b[ni], acc[mi][ni], 0, 0, 0);
        }
        __syncthreads();
    }

    // epilogue: C/D layout col=lane&15, row=(lane>>4)*4+reg  [m89 verified]
    #pragma unroll
    for (int mi = 0; mi < 4; ++mi) {
        int row0 = row_base + wr * 64 + mi * 16 + ((lane >> 4) << 2);
        #pragma unroll
        for (int ni = 0; ni < 4; ++ni) {
            int col = col_base + wc * 64 + ni * 16 + lr;
            float bv = jb.bias ? jb.bias[col] : 0.f;
            #pragma unroll
            for (int r = 0; r < 4; ++r) {
                int row = row0 + r;
                if (row < M) {
                    float x = acc[mi][ni][r] + bv;
                    if (ACT == 1) x = fmaxf(x, 0.f);
                    if (ACT == 2) x = 1.f / (1.f + __expf(-x));
                    if constexpr (OF32)
                        ((float*)jb.C)[(size_t)row * N + col] = x;
                    else
                        ((u16*)jb.C)[(size_t)row * N + col] = f2bf(x);
                }
            }
        }
    }
}

// ---------------------------------------------------------------------------
// Merged build_x: X[r] = [ selfP[sidx[r]] (256 bf16) | mean_f nbP[nidx[r*10+f]] ]
// Half-wave (32 lanes) per row, 16 B/lane. null idx means identity.
// ---------------------------------------------------------------------------
struct BJob {
    u16* X;
    const u16* selfP;
    const int* sidx;
    const u16* nbP;
    const int* nidx;
    int roff;           // first global row of this job (ascending)
};
struct BJobs4 { BJob j[4]; };

template <int NJ>
__global__ void build_xm_k(BJobs4 bj, int total) {
    int gw = (int)((blockIdx.x * blockDim.x + threadIdx.x) >> 5);
    int hl = threadIdx.x & 31;
    if (gw >= total) return;
    BJob jb = bj.j[0];
    #pragma unroll
    for (int k = 1; k < NJ; ++k) if (gw >= bj.j[k].roff) jb = bj.j[k];
    int r = gw - jb.roff;

    int c8 = hl * 8;
    int sr = jb.sidx ? jb.sidx[r] : r;
    short8 sv = *(const short8*)&jb.selfP[(size_t)sr * 256 + c8];
    *(short8*)&jb.X[(size_t)r * 512 + c8] = sv;

    float s[8] = {};
    #pragma unroll
    for (int f = 0; f < 10; ++f) {
        int nr = jb.nidx ? jb.nidx[r * 10 + f] : r * 10 + f;
        short8 nv = *(const short8*)&jb.nbP[(size_t)nr * 256 + c8];
        #pragma unroll
        for (int jj = 0; jj < 8; ++jj) s[jj] += bf2f((u16)nv[jj]);
    }
    union { u16 u[8]; short8 v; } o;
    #pragma unroll
    for (int jj = 0; jj < 8; ++jj) o.u[jj] = f2bf(s[jj] * 0.1f);
    *(short8*)&jb.X[(size_t)r * 512 + 256 + c8] = o.v;
}

// ---------------------------------------------------------------------------
// logits[b] = sum_k hu[b,k]*hi[b,k]*wlin[k] + blin    (one wave per b)
// ---------------------------------------------------------------------------
__global__ void logits_k(const float* __restrict__ hu, const float* __restrict__ hi,
                         const float* __restrict__ wlin, const float* __restrict__ blin,
                         float* __restrict__ out, int Bn) {
    int w = (blockIdx.x * blockDim.x + threadIdx.x) >> 6;
    int lane = threadIdx.x & 63;
    if (w >= Bn) return;
    float s = 0.f;
    #pragma unroll
    for (int k = lane; k < 128; k += 64)
        s += hu[(size_t)w * 128 + k] * hi[(size_t)w * 128 + k] * wlin[k];
    #pragma unroll
    for (int off = 32; off > 0; off >>= 1) s += __shfl_down(s, off, 64);
    if (lane == 0) out[w] = s + blin[0];
}

// ---------------------------------------------------------------------------
extern "C" void kernel_launch(void* const* d_in, const int* in_sizes, int n_in,
                              void* d_out, int out_size, void* d_ws, size_t ws_size,
                              hipStream_t stream) {
    const float* user_feat = (const float*)d_in[0];
    const float* item_feat = (const float*)d_in[1];
    const float* W_pu = (const float*)d_in[2];
    const float* b_pu = (const float*)d_in[3];
    const float* W_pi = (const float*)d_in[4];
    const float* b_pi = (const float*)d_in[5];
    const float* u_self0 = (const float*)d_in[6];
    const float* u_agg0 = (const float*)d_in[7];
    const float* u_self1 = (const float*)d_in[8];
    const float* u_agg1 = (const float*)d_in[9];
    const float* i_self0 = (const float*)d_in[10];
    const float* i_agg0 = (const float*)d_in[11];
    const float* i_self1 = (const float*)d_in[12];
    const float* i_agg1 = (const float*)d_in[13];
    const float* W_lin = (const float*)d_in[14];
    const float* b_lin = (const float*)d_in[15];
    const int* src_h0 = (const int*)d_in[16];
    const int* src_h1 = (const int*)d_in[17];
    const int* src_h2 = (const int*)d_in[18];
    const int* dst_h0 = (const int*)d_in[19];
    const int* dst_h1 = (const int*)d_in[20];
    const int* dst_h2 = (const int*)d_in[21];
    float* out = (float*)d_out;

    const int NU = 50000, NI = 100000, B = 4096, BF = 40960;

    char* ws = (char*)d_ws;
    size_t off = 0;
    auto alloc = [&](size_t bytes) -> void* {
        void* p = ws + off;
        off += (bytes + 255) & ~(size_t)255;
        return p;
    };
    u16* Pu   = (u16*)alloc((size_t)NU * 256 * 2);
    u16* Pi   = (u16*)alloc((size_t)NI * 256 * 2);
    u16* X1a  = (u16*)alloc((size_t)BF * 512 * 2);
    u16* X1b  = (u16*)alloc((size_t)BF * 512 * 2);
    u16* G1a  = (u16*)alloc((size_t)BF * 256 * 2);
    u16* G1b  = (u16*)alloc((size_t)BF * 256 * 2);
    u16* X0a  = (u16*)alloc((size_t)B * 512 * 2);
    u16* X0b  = (u16*)alloc((size_t)B * 512 * 2);
    u16* G0a  = (u16*)alloc((size_t)B * 256 * 2);
    u16* G0b  = (u16*)alloc((size_t)B * 256 * 2);
    u16* X2a  = (u16*)alloc((size_t)B * 512 * 2);
    u16* X2b  = (u16*)alloc((size_t)B * 512 * 2);
    float* Hu = (float*)alloc((size_t)B * 128 * 4);
    float* Hi = (float*)alloc((size_t)B * 128 * 4);
    u16* WpuT = (u16*)alloc(256 * 512 * 2);
    u16* WpiT = (u16*)alloc(256 * 512 * 2);
    u16* W0uT = (u16*)alloc(256 * 512 * 2);
    u16* W0iT = (u16*)alloc(256 * 512 * 2);
    u16* W1uT = (u16*)alloc(128 * 512 * 2);
    u16* W1iT = (u16*)alloc(128 * 512 * 2);

    // --- 1. weight prep: 6 transposed-concat bf16 layouts, one launch ---
    TCJobs tj;
    tj.A[0] = W_pu;    tj.Bm[0] = W_pu;    tj.out[0] = WpuT; tj.N[0] = 256; tj.Ka[0] = 512;
    tj.A[1] = W_pi;    tj.Bm[1] = W_pi;    tj.out[1] = WpiT; tj.N[1] = 256; tj.Ka[1] = 512;
    tj.A[2] = u_self0; tj.Bm[2] = u_agg0;  tj.out[2] = W0uT; tj.N[2] = 256; tj.Ka[2] = 256;
    tj.A[3] = i_self0; tj.Bm[3] = i_agg0;  tj.out[3] = W0iT; tj.N[3] = 256; tj.Ka[3] = 256;
    tj.A[4] = u_self1; tj.Bm[4] = u_agg1;  tj.out[4] = W1uT; tj.N[4] = 128; tj.Ka[4] = 256;
    tj.A[5] = i_self1; tj.Bm[5] = i_agg1;  tj.out[5] = W1iT; tj.N[5] = 128; tj.Ka[5] = 256;
    transcat6_k<<<dim3(512, 6), 256, 0, stream>>>(tj);

    // --- 2. both projections, one launch: P = sigmoid(feat @ W + b) ---
    const int ptu = ((NU + 127) / 128) * 2;          // 782
    const int pti = ((NI + 127) / 128) * 2;          // 1564
    GJobs4 pj;
    pj.j[0] = {user_feat, WpuT, b_pu, Pu, NU, 2, 0};
    pj.j[1] = {item_feat, WpiT, b_pi, Pi, NI, 2, ptu};
    pj.j[2] = pj.j[1]; pj.j[3] = pj.j[1];
    gemm_k<2, true, 2, false><<<ptu + pti, 256, 0, stream>>>(pj);

    // --- 3. all four gather/mean builds, one launch ---
    BJobs4 b1;
    b1.j[0] = {X1a, Pi, src_h1, Pu, src_h2, 0};
    b1.j[1] = {X1b, Pu, dst_h1, Pi, dst_h2, BF};
    b1.j[2] = {X0a, Pu, src_h0, Pi, src_h1, 2 * BF};
    b1.j[3] = {X0b, Pi, dst_h0, Pu, dst_h1, 2 * BF + B};
    const int tot1 = 2 * BF + 2 * B;                 // 90112
    build_xm_k<4><<<tot1 / 8, 256, 0, stream>>>(b1, tot1);

    // --- 4. all four SAGE layer-0 GEMMs (relu, bf16 out), one launch ---
    GJobs4 sj;
    sj.j[0] = {X1a, W0uT, nullptr, G1a, BF, 2, 0};
    sj.j[1] = {X1b, W0iT, nullptr, G1b, BF, 2, 640};
    sj.j[2] = {X0a, W0uT, nullptr, G0a, B, 2, 1280};
    sj.j[3] = {X0b, W0iT, nullptr, G0b, B, 2, 1344};
    gemm_k<4, false, 1, false><<<1408, 256, 0, stream>>>(sj);

    // --- 5. hop-0 concat builds (identity indices), one launch ---
    BJobs4 b2;
    b2.j[0] = {X2a, G0a, nullptr, G1a, nullptr, 0};
    b2.j[1] = {X2b, G0b, nullptr, G1b, nullptr, B};
    b2.j[2] = b2.j[1]; b2.j[3] = b2.j[1];
    build_xm_k<2><<<(2 * B) / 8, 256, 0, stream>>>(b2, 2 * B);

    // --- 6. both final GEMMs (no act, f32 out), one launch ---
    GJobs4 fj;
    fj.j[0] = {X2a, W1uT, nullptr, Hu, B, 1, 0};
    fj.j[1] = {X2b, W1iT, nullptr, Hi, B, 1, 32};
    fj.j[2] = fj.j[1]; fj.j[3] = fj.j[1];
    gemm_k<2, false, 0, true><<<64, 256, 0, stream>>>(fj);

    // --- 7. final logits ---
    logits_k<<<B / 4, 256, 0, stream>>>(Hu, Hi, W_lin, b_lin, out, B);
}